// Round 12
// baseline (9148.093 us; speedup 1.0000x reference)
//
#include <hip/hip_runtime.h>
#include <hip/hip_bf16.h>
#include <math.h>

typedef __hip_bfloat16 bf16;

constexpr int NB=2048, NJ=7, ND=128, NHD=8, NLYR=4, NFF=512, NTR=35, NAS=70;
// padded LDS row strides (all ≡ 4 mod 32 -> bank = 4*row + col, conflict-free row spread)
constexpr int SD=132, S256=260, S384=388, S512=516;

struct KArgs { const void* p[54]; void* out; const void* flag; };

__device__ __forceinline__ float bfbits(unsigned short s){ return __uint_as_float(((unsigned)s)<<16); }
__device__ __forceinline__ float ldv(const float* p, size_t i){ return p[i]; }
__device__ __forceinline__ float ldv(const bf16* p, size_t i){ return __bfloat162float(p[i]); }
__device__ __forceinline__ void ldv4(const float* p, size_t i, float* o){
  const float4 v=*reinterpret_cast<const float4*>(p+i);
  o[0]=v.x; o[1]=v.y; o[2]=v.z; o[3]=v.w;
}
__device__ __forceinline__ void ldv4(const bf16* p, size_t i, float* o){
  unsigned long long u=*reinterpret_cast<const unsigned long long*>((const unsigned short*)p+i);
  o[0]=bfbits((unsigned short)u);
  o[1]=bfbits((unsigned short)(u>>16));
  o[2]=bfbits((unsigned short)(u>>32));
  o[3]=bfbits((unsigned short)(u>>48));
}
__device__ __forceinline__ void stv(float* p, size_t i, float v){ p[i]=v; }
__device__ __forceinline__ void stv(bf16* p, size_t i, float v){ p[i]=__float2bfloat16(v); }
__device__ __forceinline__ float gelu_f(float x){ return 0.5f*x*(1.0f+erff(x*0.70710678118654752f)); }

__device__ void build_trips(int* tr){
  int n=0;
  for(int a=0;a<NJ;a++)for(int b=a+1;b<NJ;b++)for(int c=b+1;c<NJ;c++){
    tr[n*3+0]=a; tr[n*3+1]=b; tr[n*3+2]=c; n++;
  }
}
__device__ int find_tid(const int* tr,int a,int b,int c){
  for(int t=0;t<NTR;t++) if(tr[t*3]==a&&tr[t*3+1]==b&&tr[t*3+2]==c) return t;
  return 0;
}
__device__ void build_assign(const int* tr,int* isr,int* g1t,int* g2t,int* g1j,int* g2j){
  int n=0;
  for(int is=0;is<NJ;is++){
    int rem[6],m=0;
    for(int j=0;j<NJ;j++) if(j!=is) rem[m++]=j;
    for(int i=0;i<6;i++)for(int jj=i+1;jj<6;jj++)for(int k=jj+1;k<6;k++){
      int c0=rem[i],c1=rem[jj],c2=rem[k];
      int comp[3],q=0;
      for(int r=0;r<6;r++){ int v=rem[r]; if(v!=c0&&v!=c1&&v!=c2) comp[q++]=v; }
      bool lt=(c0<comp[0])||(c0==comp[0]&&(c1<comp[1]||(c1==comp[1]&&c2<comp[2])));
      if(lt){
        isr[n]=is;
        g1j[n*3]=c0; g1j[n*3+1]=c1; g1j[n*3+2]=c2;
        g2j[n*3]=comp[0]; g2j[n*3+1]=comp[1]; g2j[n*3+2]=comp[2];
        g1t[n]=find_tid(tr,c0,c1,c2);
        g2t[n]=find_tid(tr,comp[0],comp[1],comp[2]);
        n++;
      }
    }
  }
}

// LayerNorm over 128 cols with explicit strides; 32 lanes/row, shuffle reduce
template<typename T>
__device__ void lnr(const float* src, int ASs, float* dst, int ASd, const T* g, const T* bb,
                    float* mu, float* rs, int rows, int tid, int NT){
  for(int r0=0;r0<rows;r0+=(NT>>5)){
    int row=r0+(tid>>5), lane=tid&31;
    if(row<rows){
      const float* s=src+row*ASs;
      float m=0.f,v=0.f;
      for(int d=lane;d<ND;d+=32){ float t=s[d]; m+=t; v+=t*t; }
      for(int off=16;off>0;off>>=1){ m+=__shfl_down(m,off,32); v+=__shfl_down(v,off,32); }
      if(lane==0){ m*=(1.f/ND); float vv=v*(1.f/ND)-m*m; mu[row]=m; rs[row]=rsqrtf(fmaxf(vv,0.f)+1e-5f); }
    }
    __syncthreads();
  }
  for(int idx=tid; idx<rows*ND; idx+=NT){
    int j=idx>>7, d=idx&127;
    dst[j*ASd+d]=(src[j*ASs+d]-mu[j])*rs[j]*ldv(g,d)+ldv(bb,d);
  }
  __syncthreads();
}

// out[i*ASo + n] = act(a[i*ASa + k] @ W[K x N] + bias). Row i = tid % RB so
// RB lanes of a wave share one W address (broadcast). Compile-time K,N enable
// full unroll + deep load pipelining (the R11 latency fix).
template<int K, int N, typename T>
__device__ void mm4b(const float* a, int ASa, const T* W, const T* bias, float* out, int ASo,
                     int M, int tid, int NT, int act, bool accum, int RB){
  constexpr int NQ=N>>2;
  int CGS=NT/RB;
  if(tid<CGS*RB){
    int i=tid%RB, cg0=tid/RB;
    if(i<M){
      const float* ar=a+i*ASa;
      for(int cg=cg0; cg<NQ; cg+=CGS){
        int k4=cg<<2;
        float acc[4];
        if(bias) ldv4(bias,k4,acc);
        else { acc[0]=0.f;acc[1]=0.f;acc[2]=0.f;acc[3]=0.f; }
        #pragma unroll 16
        for(int d=0; d<K; d++){
          float w[4]; ldv4(W,(size_t)d*N+k4,w);
          float av=ar[d];
          acc[0]+=av*w[0]; acc[1]+=av*w[1]; acc[2]+=av*w[2]; acc[3]+=av*w[3];
        }
        int o=i*ASo+k4;
        #pragma unroll
        for(int j=0;j<4;j++){
          float v=acc[j];
          if(act==1) v=fmaxf(v,0.f); else if(act==2) v=gelu_f(v);
          if(accum) out[o+j]+=v; else out[o+j]=v;
        }
      }
    }
  }
  __syncthreads();
}

__global__ void k_detect(const unsigned short* w, int n, unsigned* flag){
  __shared__ int bad[256];
  int tid=threadIdx.x;
  int my=0;
  for(int i=tid;i<n;i+=256){
    unsigned e=(w[i]>>7)&0xFFu;
    if(e>=134u) my=1;
  }
  bad[tid]=my;
  __syncthreads();
  if(tid==0){
    int any=0; for(int i=0;i<256;i++) any|=bad[i];
    flag[0]= any?1u:0u;   // 1 => inputs fp32; 0 => bf16
  }
}

// ---------------- phase bodies ----------------

template<typename T>
__device__ void phase_embed(const T* fm, const T* Win, const T* bin,
                            const T* ptw, const T* drw, const T* mw,
                            float* xS, float* biasS, float* scratch, int b, int tid, int NT){
  float* fE =scratch+0;  float* fpx=scratch+8;  float* fpy=scratch+16; float* fpz=scratch+24;
  float* flp=scratch+32; float* fet=scratch+40; float* fcp=scratch+48; float* fsp=scratch+56;
  float* fph=scratch+64; float* fms=scratch+72;
  if(tid<NJ){
    size_t base=((size_t)b*NJ+tid)*4;
    float e=ldv(fm,base+0), x_=ldv(fm,base+1), y_=ldv(fm,base+2), z_=ldv(fm,base+3);
    float pt=fmaxf(sqrtf(x_*x_+y_*y_),1e-8f);
    fE[tid]=e; fpx[tid]=x_; fpy[tid]=y_; fpz[tid]=z_;
    flp[tid]=logf(pt);
    fet[tid]=asinhf(z_/pt);
    fph[tid]=atan2f(y_,x_);
    fms[tid]=sqrtf(fmaxf(e*e-x_*x_-y_*y_-z_*z_,1e-8f));
    fcp[tid]=x_/pt; fsp[tid]=y_/pt;
  }
  __syncthreads();
  for(int idx=tid; idx<NJ*ND; idx+=NT){
    int j=idx>>7, d=idx&127;
    float in8[8]={fE[j],fpx[j],fpy[j],fpz[j],flp[j],fet[j],fph[j],fms[j]};
    float acc=ldv(bin,d);
    for(int c=0;c<8;c++) acc += in8[c]*ldv(Win,c*ND+d);
    xS[j*SD+d]=acc;
  }
  for(int idx=tid; idx<NHD*NJ*NJ; idx+=NT){
    int h=idx/49, r=idx%49, i=r/7, jj=r%7;
    float ptb=flp[i]-flp[jj];
    float deta=fet[i]-fet[jj];
    float cd=fcp[i]*fcp[jj]+fsp[i]*fsp[jj];
    cd=fminf(fmaxf(cd,-1.0f+1e-7f),1.0f-1e-7f);
    float ac=acosf(cd);
    float dr=sqrtf(deta*deta+ac*ac);
    float Es=fE[i]+fE[jj];
    float sx=fpx[i]+fpx[jj], sy=fpy[i]+fpy[jj], sz=fpz[i]+fpz[jj];
    float mb=0.5f*logf(fmaxf(Es*Es-(sx*sx+sy*sy+sz*sz),1e-8f));
    biasS[idx]=ldv(ptw,h)*ptb+ldv(drw,h)*dr+ldv(mw,h)*mb;
  }
  __syncthreads();
}

template<typename T>
__device__ void phase_enc(float* xS, const float* biasS, float* P, float* muS, float* rsS,
    const T* eWqkv,const T* ebqkv,const T* eWo,const T* ebo,
    const T* eg1,const T* eb1,const T* eg2,const T* eb2,
    const T* eW1,const T* ebb1,const T* eW2,const T* ebb2, int tid, int NT){
  float* h  =P+0;     // 924
  float* qkv=P+924;   // 7*388 = 2716 -> 3640
  float* att=P+3640;  // 924 -> 4564
  float* sb =P+4564;  // 392 -> 4956
  float* ff =P+924;   // 7*516 = 3612 (aliases qkv+att, disjoint in time)
  for(int l=0;l<NLYR;l++){
    lnr(xS,SD,h,SD,eg1+l*ND,eb1+l*ND,muS,rsS,NJ,tid,NT);
    mm4b<128,384>(h,SD,eWqkv+(size_t)l*ND*3*ND,ebqkv+l*3*ND,qkv,S384,NJ,tid,NT,0,false,8);
    for(int idx=tid;idx<NHD*NJ*NJ;idx+=NT){
      int hh=idx/49, r=idx%49, i=r/7, jj=r%7;
      float acc=0.f;
      const float* qr=&qkv[i*S384+hh*16];
      const float* kr=&qkv[jj*S384+128+hh*16];
      for(int d=0;d<16;d++) acc+=qr[d]*kr[d];
      sb[idx]=acc*0.25f+biasS[idx];
    }
    __syncthreads();
    if(tid<NHD*NJ){
      float* s=&sb[tid*7];
      float mx=s[0]; for(int j=1;j<7;j++) mx=fmaxf(mx,s[j]);
      float sm=0.f; for(int j=0;j<7;j++){ s[j]=expf(s[j]-mx); sm+=s[j]; }
      float inv=1.0f/sm; for(int j=0;j<7;j++) s[j]*=inv;
    }
    __syncthreads();
    for(int idx=tid;idx<NJ*ND;idx+=NT){
      int i=idx>>7, d=idx&127, hh=d>>4;
      float acc=0.f;
      for(int j=0;j<7;j++) acc+=sb[(hh*7+i)*7+j]*qkv[j*S384+256+d];
      att[i*SD+d]=acc;
    }
    __syncthreads();
    mm4b<128,128>(att,SD,eWo+(size_t)l*ND*ND,ebo+l*ND,xS,SD,NJ,tid,NT,0,true,8);
    lnr(xS,SD,h,SD,eg2+l*ND,eb2+l*ND,muS,rsS,NJ,tid,NT);
    mm4b<128,512>(h,SD,eW1+(size_t)l*ND*NFF,ebb1+l*NFF,ff,S512,NJ,tid,NT,1,false,8);
    mm4b<512,128>(ff,S512,eW2+(size_t)l*NFF*ND,ebb2+l*ND,xS,SD,NJ,tid,NT,0,true,8);
  }
}

// triplet-mean projection: 8 triplets in low lane bits (bias/W broadcast), out stride SD
template<typename T>
__device__ void trip_proj(const float* xS, const int* trS, const T* W, const T* bias,
                          float* out, int tid, int NT){
  int CGS=NT>>3;
  for(int base=0;base<NTR;base+=8){
    int t=base+(tid&7);
    if(t<NTR){
      int a0=trS[t*3]*SD, a1=trS[t*3+1]*SD, a2=trS[t*3+2]*SD;
      for(int cg=tid>>3; cg<32; cg+=CGS){
        int k4=cg<<2;
        float acc[4]; ldv4(bias,k4,acc);
        #pragma unroll 16
        for(int c=0;c<ND;c++){
          float tv=(xS[a0+c]+xS[a1+c]+xS[a2+c])*(1.0f/3.0f);
          float w[4]; ldv4(W,(size_t)c*ND+k4,w);
          acc[0]+=tv*w[0]; acc[1]+=tv*w[1]; acc[2]+=tv*w[2]; acc[3]+=tv*w[3];
        }
        int o=t*SD+k4;
        out[o]=acc[0]; out[o+1]=acc[1]; out[o+2]=acc[2]; out[o+3]=acc[3];
      }
    }
  }
  __syncthreads();
}

template<typename T>
__device__ void phase_tca(float* xS, float* P, float* muS, float* rsS, const int* trS,
    const T* tWq,const T* tbq,const T* tWk,const T* tbk,const T* tWv,const T* tbv,
    const T* tWo,const T* tbo,const T* tg1,const T* tb1,const T* tW1,const T* tbb1,
    const T* tW2,const T* tbb2,const T* tg2,const T* tb2, int tid, int NT){
  float* q   =P+0;     // 924
  float* kv  =P+924;   // 35*132 = 4620 -> 5544
  float* sb4 =P+5544;  // 980 -> 6524
  float* att2=P+6524;  // 924 -> 7448
  float* tff =P+0;     // 7*260 = 1820 (q,kv dead)
  const float sc=0.17677669529663687f;
  mm4b<128,128>(xS,SD,tWq,tbq,q,SD,NJ,tid,NT,0,false,8);
  trip_proj(xS,trS,tWk,tbk,kv,tid,NT);     // K
  for(int idx=tid;idx<4*NJ*NTR;idx+=NT){
    int hh=idx/245, r=idx%245, i=r/35, t=r%35;
    float acc=0.f;
    const float* qr=&q[i*SD+hh*32];
    const float* kr=&kv[t*SD+hh*32];
    for(int d=0;d<32;d++) acc+=qr[d]*kr[d];
    bool mem=(trS[t*3]==i||trS[t*3+1]==i||trS[t*3+2]==i);
    sb4[idx]=acc*sc+(mem?0.0f:-1e9f);
  }
  __syncthreads();
  if(tid<4*NJ){
    float* s=&sb4[tid*35];
    float mx=-3e38f; for(int t=0;t<35;t++) mx=fmaxf(mx,s[t]);
    float sm=0.f; for(int t=0;t<35;t++){ s[t]=expf(s[t]-mx); sm+=s[t]; }
    float inv=1.0f/sm; for(int t=0;t<35;t++) s[t]*=inv;
  }
  __syncthreads();
  trip_proj(xS,trS,tWv,tbv,kv,tid,NT);     // V overwrites K
  for(int idx=tid;idx<NJ*ND;idx+=NT){
    int i=idx>>7, d=idx&127, hh=d>>5;
    float acc=0.f;
    for(int t=0;t<35;t++) acc+=sb4[(hh*7+i)*35+t]*kv[t*SD+d];
    att2[i*SD+d]=acc;
  }
  __syncthreads();
  mm4b<128,128>(att2,SD,tWo,tbo,xS,SD,NJ,tid,NT,0,true,8);
  lnr(xS,SD,xS,SD,tg1,tb1,muS,rsS,NJ,tid,NT);
  mm4b<128,256>(xS,SD,tW1,tbb1,tff,S256,NJ,tid,NT,2,false,8);
  mm4b<256,128>(tff,S256,tW2,tbb2,xS,SD,NJ,tid,NT,0,true,8);
  lnr(xS,SD,xS,SD,tg2,tb2,muS,rsS,NJ,tid,NT);
}

// ---------------- kernels ----------------

template<typename T>
__global__ __launch_bounds__(256) void k_front(KArgs A, unsigned want, float* X2, float* EVT){
  if(((const unsigned*)A.flag)[0]!=want) return;
  int b=blockIdx.x, tid=threadIdx.x;
  __shared__ float xS[NJ*SD];
  __shared__ float biasS[NHD*NJ*NJ];
  __shared__ float P[7448];
  __shared__ float muS[16], rsS[16];
  __shared__ int trS[NTR*3];
  if(tid==0) build_trips(trS);
  __syncthreads();
  phase_embed((const T*)A.p[0],(const T*)A.p[1],(const T*)A.p[2],
              (const T*)A.p[3],(const T*)A.p[4],(const T*)A.p[5],xS,biasS,P,b,tid,256);
  phase_enc(xS,biasS,P,muS,rsS,
    (const T*)A.p[6],(const T*)A.p[7],(const T*)A.p[8],(const T*)A.p[9],
    (const T*)A.p[10],(const T*)A.p[11],(const T*)A.p[12],(const T*)A.p[13],
    (const T*)A.p[14],(const T*)A.p[15],(const T*)A.p[16],(const T*)A.p[17],tid,256);
  phase_tca(xS,P,muS,rsS,trS,
    (const T*)A.p[18],(const T*)A.p[19],(const T*)A.p[20],(const T*)A.p[21],
    (const T*)A.p[22],(const T*)A.p[23],(const T*)A.p[24],(const T*)A.p[25],
    (const T*)A.p[26],(const T*)A.p[27],(const T*)A.p[28],(const T*)A.p[29],
    (const T*)A.p[30],(const T*)A.p[31],(const T*)A.p[32],(const T*)A.p[33],tid,256);
  for(int idx=tid;idx<NJ*ND;idx+=256) X2[(size_t)b*NJ*ND+idx]=xS[(idx>>7)*SD+(idx&127)];
  if(tid<ND){
    float s=0.f; for(int j=0;j<NJ;j++) s+=xS[j*SD+tid];
    EVT[(size_t)b*ND+tid]=s*(1.0f/NJ);
  }
}

// group transformer: 3 triplets (9 tokens) per block, 512 threads
template<typename T>
__global__ __launch_bounds__(512,6) void k_gt(KArgs A, unsigned want, const float* X2, float* GRP){
  if(((const unsigned*)A.flag)[0]!=want) return;
  const T* gWqkv=(const T*)A.p[34]; const T* gbqkv=(const T*)A.p[35];
  const T* gWo  =(const T*)A.p[36]; const T* gbo  =(const T*)A.p[37];
  const T* gg1  =(const T*)A.p[38]; const T* gb1  =(const T*)A.p[39];
  const T* gg2  =(const T*)A.p[40]; const T* gb2  =(const T*)A.p[41];
  const T* gW1  =(const T*)A.p[42]; const T* gbb1 =(const T*)A.p[43];
  const T* gW2  =(const T*)A.p[44]; const T* gbb2 =(const T*)A.p[45];
  int b=blockIdx.x/12, ch=blockIdx.x%12, tid=threadIdx.x;
  int c0=ch*3, tc=(NTR-c0)<3?(NTR-c0):3;
  int ntok=3*tc;
  __shared__ float jets[NJ*SD];
  __shared__ float xg[9*SD];
  __shared__ float hg[9*SD];        // also attg
  __shared__ float qkvg[9*S384];    // also ffg (9*260 fits)
  __shared__ float sbg[108];
  __shared__ float muS[16], rsS[16];
  __shared__ int trS[NTR*3];
  if(tid==0) build_trips(trS);
  for(int idx=tid;idx<NJ*ND;idx+=512) jets[(idx>>7)*SD+(idx&127)]=X2[(size_t)b*NJ*ND+idx];
  __syncthreads();
  const float sc=0.17677669529663687f;
  for(int idx=tid;idx<ntok*ND;idx+=512){
    int s=idx>>7, d=idx&127; int t=c0+s/3, r=s%3;
    xg[s*SD+d]=jets[trS[t*3+r]*SD+d];
  }
  __syncthreads();
  lnr(xg,SD,hg,SD,gg1,gb1,muS,rsS,ntok,tid,512);
  mm4b<128,384>(hg,SD,gWqkv,gbqkv,qkvg,S384,ntok,tid,512,0,false,9);
  for(int idx=tid;idx<tc*36;idx+=512){
    int s=idx/36, r=idx%36, hh=r/9, p=r%9, i=p/3, j=p%3;
    float acc=0.f;
    const float* qr=&qkvg[(s*3+i)*S384+hh*32];
    const float* kr=&qkvg[(s*3+j)*S384+128+hh*32];
    for(int d=0;d<32;d++) acc+=qr[d]*kr[d];
    sbg[idx]=acc*sc;
  }
  __syncthreads();
  for(int q2=tid;q2<tc*12;q2+=512){
    int s=q2/12, r2=q2%12;
    float* base=&sbg[s*36+(r2/3)*9+(r2%3)*3];
    float mx=fmaxf(base[0],fmaxf(base[1],base[2]));
    float e0=expf(base[0]-mx),e1=expf(base[1]-mx),e2=expf(base[2]-mx);
    float inv=1.0f/(e0+e1+e2);
    base[0]=e0*inv; base[1]=e1*inv; base[2]=e2*inv;
  }
  __syncthreads();
  // AV into attg (=hg; hg value no longer needed)
  for(int idx=tid;idx<ntok*ND;idx+=512){
    int sr=idx>>7, d=idx&127; int s=sr/3, i=sr%3, hh=d>>5;
    float acc=0.f;
    for(int j=0;j<3;j++) acc+=sbg[s*36+hh*9+i*3+j]*qkvg[(s*3+j)*S384+256+d];
    hg[sr*SD+d]=acc;
  }
  __syncthreads();
  mm4b<128,128>(hg,SD,gWo,gbo,xg,SD,ntok,tid,512,0,true,9);
  lnr(xg,SD,hg,SD,gg2,gb2,muS,rsS,ntok,tid,512);
  mm4b<128,256>(hg,SD,gW1,gbb1,qkvg,S256,ntok,tid,512,1,false,9);   // ffg aliases qkvg
  mm4b<256,128>(qkvg,S256,gW2,gbb2,xg,SD,ntok,tid,512,0,true,9);
  for(int idx=tid;idx<tc*ND;idx+=512){
    int s=idx>>7, d=idx&127;
    GRP[((size_t)b*NTR+c0+s)*ND+d]=
      (xg[(s*3)*SD+d]+xg[(s*3+1)*SD+d]+xg[(s*3+2)*SD+d])*(1.0f/3.0f);
  }
}

// ---------------- LDS-staged GEMM scorer (unchanged, proven) ----------------
template<typename T>
__global__ __launch_bounds__(512) void k_score(KArgs A, unsigned want,
    const float* X2, const float* EVT, const float* GRP){
  if(((const unsigned*)A.flag)[0]!=want) return;
  const T* fm =(const T*)A.p[0];
  const T* phg=(const T*)A.p[46]; const T* phb=(const T*)A.p[47];
  const T* sW1=(const T*)A.p[48]; const T* sb1=(const T*)A.p[49];
  const T* sW2=(const T*)A.p[50]; const T* sb2=(const T*)A.p[51];
  const T* sW3=(const T*)A.p[52]; const T* sb3=(const T*)A.p[53];
  T* OUT=(T*)A.out;
  int b=blockIdx.x, tid=threadIdx.x;
  int ar=tid&7, cg=tid>>3;

  __shared__ float POOL[12472];
  float* grpP=POOL;
  float* Ws  =POOL+4680;
  float* h2t =POOL+4680;
  float* h1c =POOL+8776;
  float* Fc  =POOL+10096;
  float* jets=POOL+10096;
  __shared__ float physAll[72*24];
  __shared__ float isrc[7*260];
  __shared__ float evtc[256];
  __shared__ float evtS[128];
  __shared__ float fmvS[28];
  __shared__ int trS[105];
  __shared__ int isrS[72], g1tS[72], g2tS[72], g1jS[216], g2jS[216];

  if(tid==0){
    build_trips(trS); build_assign(trS,isrS,g1tS,g2tS,g1jS,g2jS);
    for(int a=70;a<72;a++){
      isrS[a]=0; g1tS[a]=0; g2tS[a]=0;
      for(int r=0;r<3;r++){ g1jS[a*3+r]=0; g2jS[a*3+r]=0; }
    }
  }
  for(int idx=tid;idx<NTR*ND;idx+=512) grpP[(idx>>7)*132+(idx&127)]=GRP[(size_t)b*NTR*ND+idx];
  for(int idx=tid;idx<NJ*ND;idx+=512) jets[idx]=X2[(size_t)b*NJ*ND+idx];
  if(tid<ND) evtS[tid]=EVT[(size_t)b*ND+tid];
  if(tid>=128&&tid<128+NJ*4){ int q=tid-128; fmvS[q]=ldv(fm,(size_t)b*NJ*4+q); }
  __syncthreads();

  {
    int i=tid&7, k4=(tid>>3)<<2;
    const float* src=(i<7)?(jets+i*ND):evtS;
    size_t rb=(i<7)?0:(size_t)4*ND;
    float acc[4];
    if(i==7) ldv4(sb1,k4,acc); else { acc[0]=0.f;acc[1]=0.f;acc[2]=0.f;acc[3]=0.f; }
    #pragma unroll 16
    for(int d=0;d<ND;d++){
      float w[4]; ldv4(sW1,(rb+d)*2*ND+k4,w);
      float av=src[d];
      acc[0]+=av*w[0]; acc[1]+=av*w[1]; acc[2]+=av*w[2]; acc[3]+=av*w[3];
    }
    if(i<7){ int o=i*260+k4; isrc[o]=acc[0]; isrc[o+1]=acc[1]; isrc[o+2]=acc[2]; isrc[o+3]=acc[3]; }
    else   { evtc[k4]=acc[0]; evtc[k4+1]=acc[1]; evtc[k4+2]=acc[2]; evtc[k4+3]=acc[3]; }
  }
  if(tid<72*4){
    int a=tid>>2, g=tid&3;
    float* o=&physAll[a*24+g*6];
    if(a<NAS){
      float p[4];
      #pragma unroll
      for(int c=0;c<4;c++){
        float v;
        if(g==0)      v=fmvS[g1jS[a*3]*4+c]+fmvS[g1jS[a*3+1]*4+c]+fmvS[g1jS[a*3+2]*4+c];
        else if(g==1) v=fmvS[g2jS[a*3]*4+c]+fmvS[g2jS[a*3+1]*4+c]+fmvS[g2jS[a*3+2]*4+c];
        else if(g==2) v=fmvS[isrS[a]*4+c];
        else          v=fmvS[g1jS[a*3]*4+c]+fmvS[g1jS[a*3+1]*4+c]+fmvS[g1jS[a*3+2]*4+c]
                       +fmvS[g2jS[a*3]*4+c]+fmvS[g2jS[a*3+1]*4+c]+fmvS[g2jS[a*3+2]*4+c];
        p[c]=v;
      }
      float E=p[0], x_=p[1], y_=p[2], z_=p[3];
      float pt=sqrtf(x_*x_+y_*y_);
      float p3=sqrtf(pt*pt+z_*z_);
      float m =sqrtf(fmaxf(E*E-p3*p3,1e-8f));
      float eta=asinhf(z_/fmaxf(pt,1e-8f));
      float ph=atan2f(y_,x_);
      o[0]=m; o[1]=pt; o[2]=eta; o[3]=ph; o[4]=E; o[5]=p3;
    } else { o[0]=0;o[1]=0;o[2]=0;o[3]=0;o[4]=0;o[5]=0; }
  }
  __syncthreads();
  if(tid<72){
    float* o=&physAll[tid*24];
    float m=0.f; for(int c=0;c<24;c++) m+=o[c]; m*=(1.0f/24.0f);
    float v=0.f; for(int c=0;c<24;c++){ float t=o[c]-m; v+=t*t; } v*=(1.0f/24.0f);
    float r=rsqrtf(v+1e-5f);
    for(int c=0;c<24;c++) o[c]=(o[c]-m)*r*ldv(phg,c)+ldv(phb,c);
  }
  __syncthreads();

  for(int t=0;t<2;t++){
    int tbase=t*40;
    int ns=(t==0)?5:4;
    float acc[5][4];
    #pragma unroll
    for(int s=0;s<5;s++){ acc[s][0]=0.f;acc[s][1]=0.f;acc[s][2]=0.f;acc[s][3]=0.f; }

    for(int kc=0;kc<408;kc+=16){
      int csz=(408-kc)<16?(408-kc):16;
      for(int idx4=tid*4; idx4<csz*256; idx4+=2048){
        int d=idx4>>8, n=idx4&255;
        int c=kc+d;
        size_t r=(c<384)? (size_t)(ND+c) : (size_t)(5*ND+(c-384));
        float w[4]; ldv4(sW1,r*2*ND+n,w);
        Ws[d*256+n]=w[0]; Ws[d*256+n+1]=w[1]; Ws[d*256+n+2]=w[2]; Ws[d*256+n+3]=w[3];
      }
      for(int idx=tid; idx<72*16; idx+=512){
        int a=idx>>4, d=idx&15;
        if(d<csz){
          int c=kc+d;
          float f;
          if(c<384){
            int cc=c&127, kind=c>>7;
            float u=grpP[g1tS[a]*132+cc], w=grpP[g2tS[a]*132+cc];
            f=(kind==0)?(u+w):(kind==1)?(u*w):(u-w)*(u-w);
          } else f=physAll[a*24+(c-384)];
          Fc[a*17+d]=f;
        }
      }
      __syncthreads();
      for(int d=0;d<csz;d++){
        const float* wp=&Ws[d*256+(cg<<2)];
        float w0=wp[0],w1=wp[1],w2=wp[2],w3=wp[3];
        #pragma unroll
        for(int s=0;s<5;s++){
          if(s<ns){
            float f=Fc[(tbase+ar+8*s)*17+d];
            acc[s][0]+=f*w0; acc[s][1]+=f*w1; acc[s][2]+=f*w2; acc[s][3]+=f*w3;
          }
        }
      }
      __syncthreads();
    }
    float h1r[5][4];
    #pragma unroll
    for(int s=0;s<5;s++){
      if(s<ns){
        int a=tbase+ar+8*s;
        int ir=isrS[a];
        #pragma unroll
        for(int j=0;j<4;j++){
          int k=(cg<<2)+j;
          h1r[s][j]=gelu_f(acc[s][j]+evtc[k]+isrc[ir*260+k]);
        }
      } else { h1r[s][0]=0;h1r[s][1]=0;h1r[s][2]=0;h1r[s][3]=0; }
    }

    float acc2[5][4];
    {
      float b2v[4]; int k4b=(cg&31)<<2; ldv4(sb2,k4b,b2v);
      #pragma unroll
      for(int s=0;s<5;s++){ acc2[s][0]=b2v[0];acc2[s][1]=b2v[1];acc2[s][2]=b2v[2];acc2[s][3]=b2v[3]; }
    }
    for(int fc=0;fc<256;fc+=32){
      if(cg>=(fc>>2)&&cg<(fc>>2)+8){
        int dcol=(cg<<2)-fc;
        #pragma unroll
        for(int s=0;s<5;s++){
          if(s<ns){
            int al=ar+8*s;
            h1c[al*33+dcol]  =h1r[s][0];
            h1c[al*33+dcol+1]=h1r[s][1];
            h1c[al*33+dcol+2]=h1r[s][2];
            h1c[al*33+dcol+3]=h1r[s][3];
          }
        }
      }
      for(int idx4=tid*4; idx4<32*128; idx4+=2048){
        int d=idx4>>7, n=idx4&127;
        float w[4]; ldv4(sW2,(size_t)(fc+d)*128+n,w);
        Ws[d*128+n]=w[0]; Ws[d*128+n+1]=w[1]; Ws[d*128+n+2]=w[2]; Ws[d*128+n+3]=w[3];
      }
      __syncthreads();
      if(cg<32){
        for(int d=0;d<32;d++){
          const float* wp=&Ws[d*128+(cg<<2)];
          float w0=wp[0],w1=wp[1],w2=wp[2],w3=wp[3];
          #pragma unroll
          for(int s=0;s<5;s++){
            if(s<ns){
              float f=h1c[(ar+8*s)*33+d];
              acc2[s][0]+=f*w0; acc2[s][1]+=f*w1; acc2[s][2]+=f*w2; acc2[s][3]+=f*w3;
            }
          }
        }
      }
      __syncthreads();
    }
    if(cg<32){
      int k4=cg<<2;
      #pragma unroll
      for(int s=0;s<5;s++){
        if(s<ns){
          int al=ar+8*s;
          h2t[al*129+k4]  =gelu_f(acc2[s][0]);
          h2t[al*129+k4+1]=gelu_f(acc2[s][1]);
          h2t[al*129+k4+2]=gelu_f(acc2[s][2]);
          h2t[al*129+k4+3]=gelu_f(acc2[s][3]);
        }
      }
    }
    __syncthreads();
    {
      int widx=tid>>6, lane=tid&63;
      int nal=(t==0)?40:30;
      for(int s2=0;s2<5;s2++){
        int al=widx+8*s2;
        if(al<nal){
          float part=h2t[al*129+lane]*ldv(sW3,lane)+h2t[al*129+64+lane]*ldv(sW3,64+lane);
          for(int off=32;off>0;off>>=1) part+=__shfl_down(part,off,64);
          if(lane==0) stv(OUT,(size_t)b*NAS+tbase+al,part+ldv(sb3,0));
        }
      }
    }
    __syncthreads();
  }
}

extern "C" void kernel_launch(void* const* d_in, const int* in_sizes, int n_in,
                              void* d_out, int out_size, void* d_ws, size_t ws_size,
                              hipStream_t stream){
  KArgs A;
  for(int i=0;i<54;i++) A.p[i]=d_in[i];
  A.out=d_out;
  A.flag=d_ws;

  float* ws=(float*)d_ws;
  float* X2  = ws+16;
  float* EVT = X2 + (size_t)NB*NJ*ND;
  float* GRP = EVT + (size_t)NB*ND;

  k_detect<<<1,256,0,stream>>>((const unsigned short*)d_in[1],1024,(unsigned*)d_ws);

  k_front<bf16> <<<NB,256,0,stream>>>(A,0u,X2,EVT);
  k_front<float><<<NB,256,0,stream>>>(A,1u,X2,EVT);
  k_gt<bf16>    <<<NB*12,512,0,stream>>>(A,0u,X2,GRP);
  k_gt<float>   <<<NB*12,512,0,stream>>>(A,1u,X2,GRP);
  k_score<bf16> <<<NB,512,0,stream>>>(A,0u,X2,EVT,GRP);
  k_score<float><<<NB,512,0,stream>>>(A,1u,X2,EVT,GRP);
}

// Round 13
// 6968.095 us; speedup vs baseline: 1.3129x; 1.3129x over previous
//
#include <hip/hip_runtime.h>
#include <hip/hip_bf16.h>
#include <math.h>

typedef __hip_bfloat16 bf16;

constexpr int NB=2048, NJ=7, ND=128, NHD=8, NLYR=4, NFF=512, NTR=35, NAS=70;
// padded LDS row strides (all ≡ 4 mod 32 -> bank = 4*row + col, conflict-free row spread)
constexpr int SD=132, S256=260, S384=388, S512=516;

struct KArgs { const void* p[54]; void* out; const void* flag; };

__device__ __forceinline__ float bfbits(unsigned short s){ return __uint_as_float(((unsigned)s)<<16); }
__device__ __forceinline__ float ldv(const float* p, size_t i){ return p[i]; }
__device__ __forceinline__ float ldv(const bf16* p, size_t i){ return __bfloat162float(p[i]); }
__device__ __forceinline__ void ldv4(const float* p, size_t i, float* o){
  const float4 v=*reinterpret_cast<const float4*>(p+i);
  o[0]=v.x; o[1]=v.y; o[2]=v.z; o[3]=v.w;
}
__device__ __forceinline__ void ldv4(const bf16* p, size_t i, float* o){
  unsigned long long u=*reinterpret_cast<const unsigned long long*>((const unsigned short*)p+i);
  o[0]=bfbits((unsigned short)u);
  o[1]=bfbits((unsigned short)(u>>16));
  o[2]=bfbits((unsigned short)(u>>32));
  o[3]=bfbits((unsigned short)(u>>48));
}
__device__ __forceinline__ void stv(float* p, size_t i, float v){ p[i]=v; }
__device__ __forceinline__ void stv(bf16* p, size_t i, float v){ p[i]=__float2bfloat16(v); }
__device__ __forceinline__ float gelu_f(float x){ return 0.5f*x*(1.0f+erff(x*0.70710678118654752f)); }

__device__ void build_trips(int* tr){
  int n=0;
  for(int a=0;a<NJ;a++)for(int b=a+1;b<NJ;b++)for(int c=b+1;c<NJ;c++){
    tr[n*3+0]=a; tr[n*3+1]=b; tr[n*3+2]=c; n++;
  }
}
__device__ int find_tid(const int* tr,int a,int b,int c){
  for(int t=0;t<NTR;t++) if(tr[t*3]==a&&tr[t*3+1]==b&&tr[t*3+2]==c) return t;
  return 0;
}
__device__ void build_assign(const int* tr,int* isr,int* g1t,int* g2t,int* g1j,int* g2j){
  int n=0;
  for(int is=0;is<NJ;is++){
    int rem[6],m=0;
    for(int j=0;j<NJ;j++) if(j!=is) rem[m++]=j;
    for(int i=0;i<6;i++)for(int jj=i+1;jj<6;jj++)for(int k=jj+1;k<6;k++){
      int c0=rem[i],c1=rem[jj],c2=rem[k];
      int comp[3],q=0;
      for(int r=0;r<6;r++){ int v=rem[r]; if(v!=c0&&v!=c1&&v!=c2) comp[q++]=v; }
      bool lt=(c0<comp[0])||(c0==comp[0]&&(c1<comp[1]||(c1==comp[1]&&c2<comp[2])));
      if(lt){
        isr[n]=is;
        g1j[n*3]=c0; g1j[n*3+1]=c1; g1j[n*3+2]=c2;
        g2j[n*3]=comp[0]; g2j[n*3+1]=comp[1]; g2j[n*3+2]=comp[2];
        g1t[n]=find_tid(tr,c0,c1,c2);
        g2t[n]=find_tid(tr,comp[0],comp[1],comp[2]);
        n++;
      }
    }
  }
}

// LayerNorm over 128 cols with explicit strides; 32 lanes/row, shuffle reduce
template<typename T>
__device__ void lnr(const float* src, int ASs, float* dst, int ASd, const T* g, const T* bb,
                    float* mu, float* rs, int rows, int tid, int NT){
  for(int r0=0;r0<rows;r0+=(NT>>5)){
    int row=r0+(tid>>5), lane=tid&31;
    if(row<rows){
      const float* s=src+row*ASs;
      float m=0.f,v=0.f;
      for(int d=lane;d<ND;d+=32){ float t=s[d]; m+=t; v+=t*t; }
      for(int off=16;off>0;off>>=1){ m+=__shfl_down(m,off,32); v+=__shfl_down(v,off,32); }
      if(lane==0){ m*=(1.f/ND); float vv=v*(1.f/ND)-m*m; mu[row]=m; rs[row]=rsqrtf(fmaxf(vv,0.f)+1e-5f); }
    }
    __syncthreads();
  }
  for(int idx=tid; idx<rows*ND; idx+=NT){
    int j=idx>>7, d=idx&127;
    dst[j*ASd+d]=(src[j*ASs+d]-mu[j])*rs[j]*ldv(g,d)+ldv(bb,d);
  }
  __syncthreads();
}

// rows-in-registers GEMM: thread owns ONE output column and all M (<=RMAX) rows.
// Per K-step: one scalar weight load feeds M FMAs (0.5 B/MAC L1 traffic);
// activation reads are wave-uniform LDS broadcasts. Weight loads lane-consecutive.
template<int K,int N,int RMAX,typename T>
__device__ void mmR(const float* a,int ASa,const T* W,const T* bias,float* out,int ASo,
                    int M,int tid,int NT,int act,bool accum){
  for(int col=tid; col<N; col+=NT){
    float acc[RMAX];
    #pragma unroll
    for(int r=0;r<RMAX;r++) acc[r]=0.f;
    #pragma unroll 4
    for(int d=0;d<K;d++){
      float w=ldv(W,(size_t)d*N+col);
      #pragma unroll
      for(int r=0;r<RMAX;r++) if(r<M) acc[r]+=a[r*ASa+d]*w;
    }
    float bv = bias? ldv(bias,col) : 0.f;
    #pragma unroll
    for(int r=0;r<RMAX;r++) if(r<M){
      float v=acc[r]+bv;
      if(act==1) v=fmaxf(v,0.f); else if(act==2) v=gelu_f(v);
      int o=r*ASo+col;
      if(accum) out[o]+=v; else out[o]=v;
    }
  }
  __syncthreads();
}

__global__ void k_detect(const unsigned short* w, int n, unsigned* flag){
  __shared__ int bad[256];
  int tid=threadIdx.x;
  int my=0;
  for(int i=tid;i<n;i+=256){
    unsigned e=(w[i]>>7)&0xFFu;
    if(e>=134u) my=1;
  }
  bad[tid]=my;
  __syncthreads();
  if(tid==0){
    int any=0; for(int i=0;i<256;i++) any|=bad[i];
    flag[0]= any?1u:0u;   // 1 => inputs fp32; 0 => bf16
  }
}

// ---------------- phase bodies ----------------

template<typename T>
__device__ void phase_embed(const T* fm, const T* Win, const T* bin,
                            const T* ptw, const T* drw, const T* mw,
                            float* xS, float* biasS, float* scratch, int b, int tid, int NT){
  float* fE =scratch+0;  float* fpx=scratch+8;  float* fpy=scratch+16; float* fpz=scratch+24;
  float* flp=scratch+32; float* fet=scratch+40; float* fcp=scratch+48; float* fsp=scratch+56;
  float* fph=scratch+64; float* fms=scratch+72;
  if(tid<NJ){
    size_t base=((size_t)b*NJ+tid)*4;
    float e=ldv(fm,base+0), x_=ldv(fm,base+1), y_=ldv(fm,base+2), z_=ldv(fm,base+3);
    float pt=fmaxf(sqrtf(x_*x_+y_*y_),1e-8f);
    fE[tid]=e; fpx[tid]=x_; fpy[tid]=y_; fpz[tid]=z_;
    flp[tid]=logf(pt);
    fet[tid]=asinhf(z_/pt);
    fph[tid]=atan2f(y_,x_);
    fms[tid]=sqrtf(fmaxf(e*e-x_*x_-y_*y_-z_*z_,1e-8f));
    fcp[tid]=x_/pt; fsp[tid]=y_/pt;
  }
  __syncthreads();
  for(int idx=tid; idx<NJ*ND; idx+=NT){
    int j=idx>>7, d=idx&127;
    float in8[8]={fE[j],fpx[j],fpy[j],fpz[j],flp[j],fet[j],fph[j],fms[j]};
    float acc=ldv(bin,d);
    for(int c=0;c<8;c++) acc += in8[c]*ldv(Win,c*ND+d);
    xS[j*SD+d]=acc;
  }
  for(int idx=tid; idx<NHD*NJ*NJ; idx+=NT){
    int h=idx/49, r=idx%49, i=r/7, jj=r%7;
    float ptb=flp[i]-flp[jj];
    float deta=fet[i]-fet[jj];
    float cd=fcp[i]*fcp[jj]+fsp[i]*fsp[jj];
    cd=fminf(fmaxf(cd,-1.0f+1e-7f),1.0f-1e-7f);
    float ac=acosf(cd);
    float dr=sqrtf(deta*deta+ac*ac);
    float Es=fE[i]+fE[jj];
    float sx=fpx[i]+fpx[jj], sy=fpy[i]+fpy[jj], sz=fpz[i]+fpz[jj];
    float mb=0.5f*logf(fmaxf(Es*Es-(sx*sx+sy*sy+sz*sz),1e-8f));
    biasS[idx]=ldv(ptw,h)*ptb+ldv(drw,h)*dr+ldv(mw,h)*mb;
  }
  __syncthreads();
}

template<typename T>
__device__ void phase_enc(float* xS, const float* biasS, float* P, float* muS, float* rsS,
    const T* eWqkv,const T* ebqkv,const T* eWo,const T* ebo,
    const T* eg1,const T* eb1,const T* eg2,const T* eb2,
    const T* eW1,const T* ebb1,const T* eW2,const T* ebb2, int tid, int NT){
  float* h  =P+0;     // 924
  float* qkv=P+924;   // 7*388 = 2716 -> 3640
  float* att=P+3640;  // 924 -> 4564
  float* sb =P+4564;  // 392 -> 4956
  float* ff =P+924;   // 7*516 = 3612 (aliases qkv+att, disjoint in time)
  for(int l=0;l<NLYR;l++){
    lnr(xS,SD,h,SD,eg1+l*ND,eb1+l*ND,muS,rsS,NJ,tid,NT);
    mmR<128,384,7>(h,SD,eWqkv+(size_t)l*ND*3*ND,ebqkv+l*3*ND,qkv,S384,NJ,tid,NT,0,false);
    for(int idx=tid;idx<NHD*NJ*NJ;idx+=NT){
      int hh=idx/49, r=idx%49, i=r/7, jj=r%7;
      float acc=0.f;
      const float* qr=&qkv[i*S384+hh*16];
      const float* kr=&qkv[jj*S384+128+hh*16];
      for(int d=0;d<16;d++) acc+=qr[d]*kr[d];
      sb[idx]=acc*0.25f+biasS[idx];
    }
    __syncthreads();
    if(tid<NHD*NJ){
      float* s=&sb[tid*7];
      float mx=s[0]; for(int j=1;j<7;j++) mx=fmaxf(mx,s[j]);
      float sm=0.f; for(int j=0;j<7;j++){ s[j]=expf(s[j]-mx); sm+=s[j]; }
      float inv=1.0f/sm; for(int j=0;j<7;j++) s[j]*=inv;
    }
    __syncthreads();
    for(int idx=tid;idx<NJ*ND;idx+=NT){
      int i=idx>>7, d=idx&127, hh=d>>4;
      float acc=0.f;
      for(int j=0;j<7;j++) acc+=sb[(hh*7+i)*7+j]*qkv[j*S384+256+d];
      att[i*SD+d]=acc;
    }
    __syncthreads();
    mmR<128,128,7>(att,SD,eWo+(size_t)l*ND*ND,ebo+l*ND,xS,SD,NJ,tid,NT,0,true);
    lnr(xS,SD,h,SD,eg2+l*ND,eb2+l*ND,muS,rsS,NJ,tid,NT);
    mmR<128,512,7>(h,SD,eW1+(size_t)l*ND*NFF,ebb1+l*NFF,ff,S512,NJ,tid,NT,1,false);
    mmR<512,128,7>(ff,S512,eW2+(size_t)l*NFF*ND,ebb2+l*ND,xS,SD,NJ,tid,NT,0,true);
  }
}

template<typename T>
__device__ void phase_tca(float* xS, float* P, float* muS, float* rsS, const int* trS,
    const T* tWq,const T* tbq,const T* tWk,const T* tbk,const T* tWv,const T* tbv,
    const T* tWo,const T* tbo,const T* tg1,const T* tb1,const T* tW1,const T* tbb1,
    const T* tW2,const T* tbb2,const T* tg2,const T* tb2, int tid, int NT){
  float* A   =P+0;      // 35*132 = 4620  (triplet means; dead after V)
  float* kv  =P+4620;   // 4620 -> 9240
  float* q   =P+9240;   // 924  -> 10164
  float* sb4 =P+10164;  // 980  -> 11144
  float* att2=P+0;      // 924 (A dead)
  float* tff =P+0;      // 1820 (att2 dead)
  const float sc=0.17677669529663687f;
  // triplet means
  for(int idx=tid;idx<NTR*ND;idx+=NT){
    int t=idx>>7, d=idx&127;
    A[t*SD+d]=(xS[trS[t*3]*SD+d]+xS[trS[t*3+1]*SD+d]+xS[trS[t*3+2]*SD+d])*(1.0f/3.0f);
  }
  __syncthreads();
  mmR<128,128,7>(xS,SD,tWq,tbq,q,SD,NJ,tid,NT,0,false);
  for(int rg=0;rg<5;rg++)   // K projection, 7 rows per pass
    mmR<128,128,7>(A+rg*7*SD,SD,tWk,tbk,kv+rg*7*SD,SD,7,tid,NT,0,false);
  for(int idx=tid;idx<4*NJ*NTR;idx+=NT){
    int hh=idx/245, r=idx%245, i=r/35, t=r%35;
    float acc=0.f;
    const float* qr=&q[i*SD+hh*32];
    const float* kr=&kv[t*SD+hh*32];
    for(int d=0;d<32;d++) acc+=qr[d]*kr[d];
    bool mem=(trS[t*3]==i||trS[t*3+1]==i||trS[t*3+2]==i);
    sb4[idx]=acc*sc+(mem?0.0f:-1e9f);
  }
  __syncthreads();
  if(tid<4*NJ){
    float* s=&sb4[tid*35];
    float mx=-3e38f; for(int t=0;t<35;t++) mx=fmaxf(mx,s[t]);
    float sm=0.f; for(int t=0;t<35;t++){ s[t]=expf(s[t]-mx); sm+=s[t]; }
    float inv=1.0f/sm; for(int t=0;t<35;t++) s[t]*=inv;
  }
  __syncthreads();
  for(int rg=0;rg<5;rg++)   // V projection overwrites kv (scores done)
    mmR<128,128,7>(A+rg*7*SD,SD,tWv,tbv,kv+rg*7*SD,SD,7,tid,NT,0,false);
  // A dead now; att2 aliases it
  for(int idx=tid;idx<NJ*ND;idx+=NT){
    int i=idx>>7, d=idx&127, hh=d>>5;
    float acc=0.f;
    for(int t=0;t<35;t++) acc+=sb4[(hh*7+i)*35+t]*kv[t*SD+d];
    att2[i*SD+d]=acc;
  }
  __syncthreads();
  mmR<128,128,7>(att2,SD,tWo,tbo,xS,SD,NJ,tid,NT,0,true);
  lnr(xS,SD,xS,SD,tg1,tb1,muS,rsS,NJ,tid,NT);
  mmR<128,256,7>(xS,SD,tW1,tbb1,tff,S256,NJ,tid,NT,2,false);
  mmR<256,128,7>(tff,S256,tW2,tbb2,xS,SD,NJ,tid,NT,0,true);
  lnr(xS,SD,xS,SD,tg2,tb2,muS,rsS,NJ,tid,NT);
}

// ---------------- kernels ----------------

template<typename T>
__global__ __launch_bounds__(256) void k_front(KArgs A, unsigned want, float* X2, float* EVT){
  if(((const unsigned*)A.flag)[0]!=want) return;
  int b=blockIdx.x, tid=threadIdx.x;
  __shared__ float xS[NJ*SD];
  __shared__ float biasS[NHD*NJ*NJ];
  __shared__ float P[11200];
  __shared__ float muS[16], rsS[16];
  __shared__ int trS[NTR*3];
  if(tid==0) build_trips(trS);
  __syncthreads();
  phase_embed((const T*)A.p[0],(const T*)A.p[1],(const T*)A.p[2],
              (const T*)A.p[3],(const T*)A.p[4],(const T*)A.p[5],xS,biasS,P,b,tid,256);
  phase_enc(xS,biasS,P,muS,rsS,
    (const T*)A.p[6],(const T*)A.p[7],(const T*)A.p[8],(const T*)A.p[9],
    (const T*)A.p[10],(const T*)A.p[11],(const T*)A.p[12],(const T*)A.p[13],
    (const T*)A.p[14],(const T*)A.p[15],(const T*)A.p[16],(const T*)A.p[17],tid,256);
  phase_tca(xS,P,muS,rsS,trS,
    (const T*)A.p[18],(const T*)A.p[19],(const T*)A.p[20],(const T*)A.p[21],
    (const T*)A.p[22],(const T*)A.p[23],(const T*)A.p[24],(const T*)A.p[25],
    (const T*)A.p[26],(const T*)A.p[27],(const T*)A.p[28],(const T*)A.p[29],
    (const T*)A.p[30],(const T*)A.p[31],(const T*)A.p[32],(const T*)A.p[33],tid,256);
  for(int idx=tid;idx<NJ*ND;idx+=256) X2[(size_t)b*NJ*ND+idx]=xS[(idx>>7)*SD+(idx&127)];
  if(tid<ND){
    float s=0.f; for(int j=0;j<NJ;j++) s+=xS[j*SD+tid];
    EVT[(size_t)b*ND+tid]=s*(1.0f/NJ);
  }
}

// group transformer: 3 triplets (9 tokens) per block, 512 threads
template<typename T>
__global__ __launch_bounds__(512,6) void k_gt(KArgs A, unsigned want, const float* X2, float* GRP){
  if(((const unsigned*)A.flag)[0]!=want) return;
  const T* gWqkv=(const T*)A.p[34]; const T* gbqkv=(const T*)A.p[35];
  const T* gWo  =(const T*)A.p[36]; const T* gbo  =(const T*)A.p[37];
  const T* gg1  =(const T*)A.p[38]; const T* gb1  =(const T*)A.p[39];
  const T* gg2  =(const T*)A.p[40]; const T* gb2  =(const T*)A.p[41];
  const T* gW1  =(const T*)A.p[42]; const T* gbb1 =(const T*)A.p[43];
  const T* gW2  =(const T*)A.p[44]; const T* gbb2 =(const T*)A.p[45];
  int b=blockIdx.x/12, ch=blockIdx.x%12, tid=threadIdx.x;
  int c0=ch*3, tc=(NTR-c0)<3?(NTR-c0):3;
  int ntok=3*tc;
  __shared__ float jets[NJ*SD];
  __shared__ float xg[9*SD];
  __shared__ float hg[9*SD];        // also attg
  __shared__ float qkvg[9*S384];    // also ffg (9*260 fits)
  __shared__ float sbg[108];
  __shared__ float muS[16], rsS[16];
  __shared__ int trS[NTR*3];
  if(tid==0) build_trips(trS);
  for(int idx=tid;idx<NJ*ND;idx+=512) jets[(idx>>7)*SD+(idx&127)]=X2[(size_t)b*NJ*ND+idx];
  __syncthreads();
  const float sc=0.17677669529663687f;
  for(int idx=tid;idx<ntok*ND;idx+=512){
    int s=idx>>7, d=idx&127; int t=c0+s/3, r=s%3;
    xg[s*SD+d]=jets[trS[t*3+r]*SD+d];
  }
  __syncthreads();
  lnr(xg,SD,hg,SD,gg1,gb1,muS,rsS,ntok,tid,512);
  mmR<128,384,9>(hg,SD,gWqkv,gbqkv,qkvg,S384,ntok,tid,512,0,false);
  for(int idx=tid;idx<tc*36;idx+=512){
    int s=idx/36, r=idx%36, hh=r/9, p=r%9, i=p/3, j=p%3;
    float acc=0.f;
    const float* qr=&qkvg[(s*3+i)*S384+hh*32];
    const float* kr=&qkvg[(s*3+j)*S384+128+hh*32];
    for(int d=0;d<32;d++) acc+=qr[d]*kr[d];
    sbg[idx]=acc*sc;
  }
  __syncthreads();
  for(int q2=tid;q2<tc*12;q2+=512){
    int s=q2/12, r2=q2%12;
    float* base=&sbg[s*36+(r2/3)*9+(r2%3)*3];
    float mx=fmaxf(base[0],fmaxf(base[1],base[2]));
    float e0=expf(base[0]-mx),e1=expf(base[1]-mx),e2=expf(base[2]-mx);
    float inv=1.0f/(e0+e1+e2);
    base[0]=e0*inv; base[1]=e1*inv; base[2]=e2*inv;
  }
  __syncthreads();
  // AV into attg (=hg; hg value no longer needed)
  for(int idx=tid;idx<ntok*ND;idx+=512){
    int sr=idx>>7, d=idx&127; int s=sr/3, i=sr%3, hh=d>>5;
    float acc=0.f;
    for(int j=0;j<3;j++) acc+=sbg[s*36+hh*9+i*3+j]*qkvg[(s*3+j)*S384+256+d];
    hg[sr*SD+d]=acc;
  }
  __syncthreads();
  mmR<128,128,9>(hg,SD,gWo,gbo,xg,SD,ntok,tid,512,0,true);
  lnr(xg,SD,hg,SD,gg2,gb2,muS,rsS,ntok,tid,512);
  mmR<128,256,9>(hg,SD,gW1,gbb1,qkvg,S256,ntok,tid,512,1,false);   // ffg aliases qkvg
  mmR<256,128,9>(qkvg,S256,gW2,gbb2,xg,SD,ntok,tid,512,0,true);
  for(int idx=tid;idx<tc*ND;idx+=512){
    int s=idx>>7, d=idx&127;
    GRP[((size_t)b*NTR+c0+s)*ND+d]=
      (xg[(s*3)*SD+d]+xg[(s*3+1)*SD+d]+xg[(s*3+2)*SD+d])*(1.0f/3.0f);
  }
}

// ---------------- LDS-staged GEMM scorer (unchanged, proven) ----------------
template<typename T>
__global__ __launch_bounds__(512) void k_score(KArgs A, unsigned want,
    const float* X2, const float* EVT, const float* GRP){
  if(((const unsigned*)A.flag)[0]!=want) return;
  const T* fm =(const T*)A.p[0];
  const T* phg=(const T*)A.p[46]; const T* phb=(const T*)A.p[47];
  const T* sW1=(const T*)A.p[48]; const T* sb1=(const T*)A.p[49];
  const T* sW2=(const T*)A.p[50]; const T* sb2=(const T*)A.p[51];
  const T* sW3=(const T*)A.p[52]; const T* sb3=(const T*)A.p[53];
  T* OUT=(T*)A.out;
  int b=blockIdx.x, tid=threadIdx.x;
  int ar=tid&7, cg=tid>>3;

  __shared__ float POOL[12472];
  float* grpP=POOL;
  float* Ws  =POOL+4680;
  float* h2t =POOL+4680;
  float* h1c =POOL+8776;
  float* Fc  =POOL+10096;
  float* jets=POOL+10096;
  __shared__ float physAll[72*24];
  __shared__ float isrc[7*260];
  __shared__ float evtc[256];
  __shared__ float evtS[128];
  __shared__ float fmvS[28];
  __shared__ int trS[105];
  __shared__ int isrS[72], g1tS[72], g2tS[72], g1jS[216], g2jS[216];

  if(tid==0){
    build_trips(trS); build_assign(trS,isrS,g1tS,g2tS,g1jS,g2jS);
    for(int a=70;a<72;a++){
      isrS[a]=0; g1tS[a]=0; g2tS[a]=0;
      for(int r=0;r<3;r++){ g1jS[a*3+r]=0; g2jS[a*3+r]=0; }
    }
  }
  for(int idx=tid;idx<NTR*ND;idx+=512) grpP[(idx>>7)*132+(idx&127)]=GRP[(size_t)b*NTR*ND+idx];
  for(int idx=tid;idx<NJ*ND;idx+=512) jets[idx]=X2[(size_t)b*NJ*ND+idx];
  if(tid<ND) evtS[tid]=EVT[(size_t)b*ND+tid];
  if(tid>=128&&tid<128+NJ*4){ int q=tid-128; fmvS[q]=ldv(fm,(size_t)b*NJ*4+q); }
  __syncthreads();

  {
    int i=tid&7, k4=(tid>>3)<<2;
    const float* src=(i<7)?(jets+i*ND):evtS;
    size_t rb=(i<7)?0:(size_t)4*ND;
    float acc[4];
    if(i==7) ldv4(sb1,k4,acc); else { acc[0]=0.f;acc[1]=0.f;acc[2]=0.f;acc[3]=0.f; }
    for(int d=0;d<ND;d++){
      float w[4]; ldv4(sW1,(rb+d)*2*ND+k4,w);
      float av=src[d];
      acc[0]+=av*w[0]; acc[1]+=av*w[1]; acc[2]+=av*w[2]; acc[3]+=av*w[3];
    }
    if(i<7){ int o=i*260+k4; isrc[o]=acc[0]; isrc[o+1]=acc[1]; isrc[o+2]=acc[2]; isrc[o+3]=acc[3]; }
    else   { evtc[k4]=acc[0]; evtc[k4+1]=acc[1]; evtc[k4+2]=acc[2]; evtc[k4+3]=acc[3]; }
  }
  if(tid<72*4){
    int a=tid>>2, g=tid&3;
    float* o=&physAll[a*24+g*6];
    if(a<NAS){
      float p[4];
      #pragma unroll
      for(int c=0;c<4;c++){
        float v;
        if(g==0)      v=fmvS[g1jS[a*3]*4+c]+fmvS[g1jS[a*3+1]*4+c]+fmvS[g1jS[a*3+2]*4+c];
        else if(g==1) v=fmvS[g2jS[a*3]*4+c]+fmvS[g2jS[a*3+1]*4+c]+fmvS[g2jS[a*3+2]*4+c];
        else if(g==2) v=fmvS[isrS[a]*4+c];
        else          v=fmvS[g1jS[a*3]*4+c]+fmvS[g1jS[a*3+1]*4+c]+fmvS[g1jS[a*3+2]*4+c]
                       +fmvS[g2jS[a*3]*4+c]+fmvS[g2jS[a*3+1]*4+c]+fmvS[g2jS[a*3+2]*4+c];
        p[c]=v;
      }
      float E=p[0], x_=p[1], y_=p[2], z_=p[3];
      float pt=sqrtf(x_*x_+y_*y_);
      float p3=sqrtf(pt*pt+z_*z_);
      float m =sqrtf(fmaxf(E*E-p3*p3,1e-8f));
      float eta=asinhf(z_/fmaxf(pt,1e-8f));
      float ph=atan2f(y_,x_);
      o[0]=m; o[1]=pt; o[2]=eta; o[3]=ph; o[4]=E; o[5]=p3;
    } else { o[0]=0;o[1]=0;o[2]=0;o[3]=0;o[4]=0;o[5]=0; }
  }
  __syncthreads();
  if(tid<72){
    float* o=&physAll[tid*24];
    float m=0.f; for(int c=0;c<24;c++) m+=o[c]; m*=(1.0f/24.0f);
    float v=0.f; for(int c=0;c<24;c++){ float t=o[c]-m; v+=t*t; } v*=(1.0f/24.0f);
    float r=rsqrtf(v+1e-5f);
    for(int c=0;c<24;c++) o[c]=(o[c]-m)*r*ldv(phg,c)+ldv(phb,c);
  }
  __syncthreads();

  for(int t=0;t<2;t++){
    int tbase=t*40;
    int ns=(t==0)?5:4;
    float acc[5][4];
    #pragma unroll
    for(int s=0;s<5;s++){ acc[s][0]=0.f;acc[s][1]=0.f;acc[s][2]=0.f;acc[s][3]=0.f; }

    for(int kc=0;kc<408;kc+=16){
      int csz=(408-kc)<16?(408-kc):16;
      for(int idx4=tid*4; idx4<csz*256; idx4+=2048){
        int d=idx4>>8, n=idx4&255;
        int c=kc+d;
        size_t r=(c<384)? (size_t)(ND+c) : (size_t)(5*ND+(c-384));
        float w[4]; ldv4(sW1,r*2*ND+n,w);
        Ws[d*256+n]=w[0]; Ws[d*256+n+1]=w[1]; Ws[d*256+n+2]=w[2]; Ws[d*256+n+3]=w[3];
      }
      for(int idx=tid; idx<72*16; idx+=512){
        int a=idx>>4, d=idx&15;
        if(d<csz){
          int c=kc+d;
          float f;
          if(c<384){
            int cc=c&127, kind=c>>7;
            float u=grpP[g1tS[a]*132+cc], w=grpP[g2tS[a]*132+cc];
            f=(kind==0)?(u+w):(kind==1)?(u*w):(u-w)*(u-w);
          } else f=physAll[a*24+(c-384)];
          Fc[a*17+d]=f;
        }
      }
      __syncthreads();
      for(int d=0;d<csz;d++){
        const float* wp=&Ws[d*256+(cg<<2)];
        float w0=wp[0],w1=wp[1],w2=wp[2],w3=wp[3];
        #pragma unroll
        for(int s=0;s<5;s++){
          if(s<ns){
            float f=Fc[(tbase+ar+8*s)*17+d];
            acc[s][0]+=f*w0; acc[s][1]+=f*w1; acc[s][2]+=f*w2; acc[s][3]+=f*w3;
          }
        }
      }
      __syncthreads();
    }
    float h1r[5][4];
    #pragma unroll
    for(int s=0;s<5;s++){
      if(s<ns){
        int a=tbase+ar+8*s;
        int ir=isrS[a];
        #pragma unroll
        for(int j=0;j<4;j++){
          int k=(cg<<2)+j;
          h1r[s][j]=gelu_f(acc[s][j]+evtc[k]+isrc[ir*260+k]);
        }
      } else { h1r[s][0]=0;h1r[s][1]=0;h1r[s][2]=0;h1r[s][3]=0; }
    }

    float acc2[5][4];
    {
      float b2v[4]; int k4b=(cg&31)<<2; ldv4(sb2,k4b,b2v);
      #pragma unroll
      for(int s=0;s<5;s++){ acc2[s][0]=b2v[0];acc2[s][1]=b2v[1];acc2[s][2]=b2v[2];acc2[s][3]=b2v[3]; }
    }
    for(int fc=0;fc<256;fc+=32){
      if(cg>=(fc>>2)&&cg<(fc>>2)+8){
        int dcol=(cg<<2)-fc;
        #pragma unroll
        for(int s=0;s<5;s++){
          if(s<ns){
            int al=ar+8*s;
            h1c[al*33+dcol]  =h1r[s][0];
            h1c[al*33+dcol+1]=h1r[s][1];
            h1c[al*33+dcol+2]=h1r[s][2];
            h1c[al*33+dcol+3]=h1r[s][3];
          }
        }
      }
      for(int idx4=tid*4; idx4<32*128; idx4+=2048){
        int d=idx4>>7, n=idx4&127;
        float w[4]; ldv4(sW2,(size_t)(fc+d)*128+n,w);
        Ws[d*128+n]=w[0]; Ws[d*128+n+1]=w[1]; Ws[d*128+n+2]=w[2]; Ws[d*128+n+3]=w[3];
      }
      __syncthreads();
      if(cg<32){
        for(int d=0;d<32;d++){
          const float* wp=&Ws[d*128+(cg<<2)];
          float w0=wp[0],w1=wp[1],w2=wp[2],w3=wp[3];
          #pragma unroll
          for(int s=0;s<5;s++){
            if(s<ns){
              float f=h1c[(ar+8*s)*33+d];
              acc2[s][0]+=f*w0; acc2[s][1]+=f*w1; acc2[s][2]+=f*w2; acc2[s][3]+=f*w3;
            }
          }
        }
      }
      __syncthreads();
    }
    if(cg<32){
      int k4=cg<<2;
      #pragma unroll
      for(int s=0;s<5;s++){
        if(s<ns){
          int al=ar+8*s;
          h2t[al*129+k4]  =gelu_f(acc2[s][0]);
          h2t[al*129+k4+1]=gelu_f(acc2[s][1]);
          h2t[al*129+k4+2]=gelu_f(acc2[s][2]);
          h2t[al*129+k4+3]=gelu_f(acc2[s][3]);
        }
      }
    }
    __syncthreads();
    {
      int widx=tid>>6, lane=tid&63;
      int nal=(t==0)?40:30;
      for(int s2=0;s2<5;s2++){
        int al=widx+8*s2;
        if(al<nal){
          float part=h2t[al*129+lane]*ldv(sW3,lane)+h2t[al*129+64+lane]*ldv(sW3,64+lane);
          for(int off=32;off>0;off>>=1) part+=__shfl_down(part,off,64);
          if(lane==0) stv(OUT,(size_t)b*NAS+tbase+al,part+ldv(sb3,0));
        }
      }
    }
    __syncthreads();
  }
}

extern "C" void kernel_launch(void* const* d_in, const int* in_sizes, int n_in,
                              void* d_out, int out_size, void* d_ws, size_t ws_size,
                              hipStream_t stream){
  KArgs A;
  for(int i=0;i<54;i++) A.p[i]=d_in[i];
  A.out=d_out;
  A.flag=d_ws;

  float* ws=(float*)d_ws;
  float* X2  = ws+16;
  float* EVT = X2 + (size_t)NB*NJ*ND;
  float* GRP = EVT + (size_t)NB*ND;

  k_detect<<<1,256,0,stream>>>((const unsigned short*)d_in[1],1024,(unsigned*)d_ws);

  k_front<bf16> <<<NB,256,0,stream>>>(A,0u,X2,EVT);
  k_front<float><<<NB,256,0,stream>>>(A,1u,X2,EVT);
  k_gt<bf16>    <<<NB*12,512,0,stream>>>(A,0u,X2,GRP);
  k_gt<float>   <<<NB*12,512,0,stream>>>(A,1u,X2,GRP);
  k_score<bf16> <<<NB,512,0,stream>>>(A,0u,X2,EVT,GRP);
  k_score<float><<<NB,512,0,stream>>>(A,1u,X2,EVT,GRP);
}

// Round 14
// 6131.309 us; speedup vs baseline: 1.4920x; 1.1365x over previous
//
#include <hip/hip_runtime.h>
#include <hip/hip_bf16.h>
#include <math.h>

typedef __hip_bfloat16 bf16;

constexpr int NB=2048, NJ=7, ND=128, NHD=8, NLYR=4, NFF=512, NTR=35, NAS=70;
// padded LDS row strides (all ≡ 4 mod 32 -> bank = 4*row + col, conflict-free row spread;
// all ≡ 0 mod 4 floats -> 16B-aligned rows for ds_read_b128)
constexpr int SD=132, S256=260, S384=388, S512=516;

struct KArgs { const void* p[54]; void* out; const void* flag; };

__device__ __forceinline__ float bfbits(unsigned short s){ return __uint_as_float(((unsigned)s)<<16); }
__device__ __forceinline__ float ldv(const float* p, size_t i){ return p[i]; }
__device__ __forceinline__ float ldv(const bf16* p, size_t i){ return __bfloat162float(p[i]); }
__device__ __forceinline__ void ldv4(const float* p, size_t i, float* o){
  const float4 v=*reinterpret_cast<const float4*>(p+i);
  o[0]=v.x; o[1]=v.y; o[2]=v.z; o[3]=v.w;
}
__device__ __forceinline__ void ldv4(const bf16* p, size_t i, float* o){
  unsigned long long u=*reinterpret_cast<const unsigned long long*>((const unsigned short*)p+i);
  o[0]=bfbits((unsigned short)u);
  o[1]=bfbits((unsigned short)(u>>16));
  o[2]=bfbits((unsigned short)(u>>32));
  o[3]=bfbits((unsigned short)(u>>48));
}
__device__ __forceinline__ void stv(float* p, size_t i, float v){ p[i]=v; }
__device__ __forceinline__ void stv(bf16* p, size_t i, float v){ p[i]=__float2bfloat16(v); }
__device__ __forceinline__ float gelu_f(float x){ return 0.5f*x*(1.0f+erff(x*0.70710678118654752f)); }

__device__ void build_trips(int* tr){
  int n=0;
  for(int a=0;a<NJ;a++)for(int b=a+1;b<NJ;b++)for(int c=b+1;c<NJ;c++){
    tr[n*3+0]=a; tr[n*3+1]=b; tr[n*3+2]=c; n++;
  }
}
__device__ int find_tid(const int* tr,int a,int b,int c){
  for(int t=0;t<NTR;t++) if(tr[t*3]==a&&tr[t*3+1]==b&&tr[t*3+2]==c) return t;
  return 0;
}
__device__ void build_assign(const int* tr,int* isr,int* g1t,int* g2t,int* g1j,int* g2j){
  int n=0;
  for(int is=0;is<NJ;is++){
    int rem[6],m=0;
    for(int j=0;j<NJ;j++) if(j!=is) rem[m++]=j;
    for(int i=0;i<6;i++)for(int jj=i+1;jj<6;jj++)for(int k=jj+1;k<6;k++){
      int c0=rem[i],c1=rem[jj],c2=rem[k];
      int comp[3],q=0;
      for(int r=0;r<6;r++){ int v=rem[r]; if(v!=c0&&v!=c1&&v!=c2) comp[q++]=v; }
      bool lt=(c0<comp[0])||(c0==comp[0]&&(c1<comp[1]||(c1==comp[1]&&c2<comp[2])));
      if(lt){
        isr[n]=is;
        g1j[n*3]=c0; g1j[n*3+1]=c1; g1j[n*3+2]=c2;
        g2j[n*3]=comp[0]; g2j[n*3+1]=comp[1]; g2j[n*3+2]=comp[2];
        g1t[n]=find_tid(tr,c0,c1,c2);
        g2t[n]=find_tid(tr,comp[0],comp[1],comp[2]);
        n++;
      }
    }
  }
}

// LayerNorm over 128 cols with explicit strides; 32 lanes/row, shuffle reduce
template<typename T>
__device__ void lnr(const float* src, int ASs, float* dst, int ASd, const T* g, const T* bb,
                    float* mu, float* rs, int rows, int tid, int NT){
  for(int r0=0;r0<rows;r0+=(NT>>5)){
    int row=r0+(tid>>5), lane=tid&31;
    if(row<rows){
      const float* s=src+row*ASs;
      float m=0.f,v=0.f;
      for(int d=lane;d<ND;d+=32){ float t=s[d]; m+=t; v+=t*t; }
      for(int off=16;off>0;off>>=1){ m+=__shfl_down(m,off,32); v+=__shfl_down(v,off,32); }
      if(lane==0){ m*=(1.f/ND); float vv=v*(1.f/ND)-m*m; mu[row]=m; rs[row]=rsqrtf(fmaxf(vv,0.f)+1e-5f); }
    }
    __syncthreads();
  }
  for(int idx=tid; idx<rows*ND; idx+=NT){
    int j=idx>>7, d=idx&127;
    dst[j*ASd+d]=(src[j*ASs+d]-mu[j])*rs[j]*ldv(g,d)+ldv(bb,d);
  }
  __syncthreads();
}

// rows-in-registers GEMM, k-vectorized + 2 columns/thread:
// thread owns cols (c, c+N/2) and all M rows. Per 4 k-steps: one ds_read_b128
// per row feeds 8 FMAs (LDS 1.5 cyc/wave-FMA); 8 lane-coalesced weight loads.
template<int K,int N,int RMAX,typename T>
__device__ void mmR(const float* a,int ASa,const T* W,const T* bias,float* out,int ASo,
                    int M,int tid,int NT,int act,bool accum){
  constexpr int NH=N/2;
  for(int col=tid; col<NH; col+=NT){
    int colB=col+NH;
    float accA[RMAX], accB[RMAX];
    #pragma unroll
    for(int r=0;r<RMAX;r++){ accA[r]=0.f; accB[r]=0.f; }
    for(int d=0;d<K;d+=4){
      float wA0=ldv(W,(size_t)(d+0)*N+col),  wA1=ldv(W,(size_t)(d+1)*N+col);
      float wA2=ldv(W,(size_t)(d+2)*N+col),  wA3=ldv(W,(size_t)(d+3)*N+col);
      float wB0=ldv(W,(size_t)(d+0)*N+colB), wB1=ldv(W,(size_t)(d+1)*N+colB);
      float wB2=ldv(W,(size_t)(d+2)*N+colB), wB3=ldv(W,(size_t)(d+3)*N+colB);
      #pragma unroll
      for(int r=0;r<RMAX;r++) if(r<M){
        float4 av=*reinterpret_cast<const float4*>(a+r*ASa+d);
        accA[r]+=av.x*wA0+av.y*wA1+av.z*wA2+av.w*wA3;
        accB[r]+=av.x*wB0+av.y*wB1+av.z*wB2+av.w*wB3;
      }
    }
    float bvA = bias? ldv(bias,col)  : 0.f;
    float bvB = bias? ldv(bias,colB) : 0.f;
    #pragma unroll
    for(int r=0;r<RMAX;r++) if(r<M){
      float vA=accA[r]+bvA, vB=accB[r]+bvB;
      if(act==1){ vA=fmaxf(vA,0.f); vB=fmaxf(vB,0.f); }
      else if(act==2){ vA=gelu_f(vA); vB=gelu_f(vB); }
      int o=r*ASo;
      if(accum){ out[o+col]+=vA; out[o+colB]+=vB; }
      else     { out[o+col]=vA;  out[o+colB]=vB;  }
    }
  }
  __syncthreads();
}

__global__ void k_detect(const unsigned short* w, int n, unsigned* flag){
  __shared__ int bad[256];
  int tid=threadIdx.x;
  int my=0;
  for(int i=tid;i<n;i+=256){
    unsigned e=(w[i]>>7)&0xFFu;
    if(e>=134u) my=1;
  }
  bad[tid]=my;
  __syncthreads();
  if(tid==0){
    int any=0; for(int i=0;i<256;i++) any|=bad[i];
    flag[0]= any?1u:0u;   // 1 => inputs fp32; 0 => bf16
  }
}

// ---------------- phase bodies ----------------

template<typename T>
__device__ void phase_embed(const T* fm, const T* Win, const T* bin,
                            const T* ptw, const T* drw, const T* mw,
                            float* xS, float* biasS, float* scratch, int b, int tid, int NT){
  float* fE =scratch+0;  float* fpx=scratch+8;  float* fpy=scratch+16; float* fpz=scratch+24;
  float* flp=scratch+32; float* fet=scratch+40; float* fcp=scratch+48; float* fsp=scratch+56;
  float* fph=scratch+64; float* fms=scratch+72;
  if(tid<NJ){
    size_t base=((size_t)b*NJ+tid)*4;
    float e=ldv(fm,base+0), x_=ldv(fm,base+1), y_=ldv(fm,base+2), z_=ldv(fm,base+3);
    float pt=fmaxf(sqrtf(x_*x_+y_*y_),1e-8f);
    fE[tid]=e; fpx[tid]=x_; fpy[tid]=y_; fpz[tid]=z_;
    flp[tid]=logf(pt);
    fet[tid]=asinhf(z_/pt);
    fph[tid]=atan2f(y_,x_);
    fms[tid]=sqrtf(fmaxf(e*e-x_*x_-y_*y_-z_*z_,1e-8f));
    fcp[tid]=x_/pt; fsp[tid]=y_/pt;
  }
  __syncthreads();
  for(int idx=tid; idx<NJ*ND; idx+=NT){
    int j=idx>>7, d=idx&127;
    float in8[8]={fE[j],fpx[j],fpy[j],fpz[j],flp[j],fet[j],fph[j],fms[j]};
    float acc=ldv(bin,d);
    for(int c=0;c<8;c++) acc += in8[c]*ldv(Win,c*ND+d);
    xS[j*SD+d]=acc;
  }
  for(int idx=tid; idx<NHD*NJ*NJ; idx+=NT){
    int h=idx/49, r=idx%49, i=r/7, jj=r%7;
    float ptb=flp[i]-flp[jj];
    float deta=fet[i]-fet[jj];
    float cd=fcp[i]*fcp[jj]+fsp[i]*fsp[jj];
    cd=fminf(fmaxf(cd,-1.0f+1e-7f),1.0f-1e-7f);
    float ac=acosf(cd);
    float dr=sqrtf(deta*deta+ac*ac);
    float Es=fE[i]+fE[jj];
    float sx=fpx[i]+fpx[jj], sy=fpy[i]+fpy[jj], sz=fpz[i]+fpz[jj];
    float mb=0.5f*logf(fmaxf(Es*Es-(sx*sx+sy*sy+sz*sz),1e-8f));
    biasS[idx]=ldv(ptw,h)*ptb+ldv(drw,h)*dr+ldv(mw,h)*mb;
  }
  __syncthreads();
}

template<typename T>
__device__ void phase_enc(float* xS, const float* biasS, float* P, float* muS, float* rsS,
    const T* eWqkv,const T* ebqkv,const T* eWo,const T* ebo,
    const T* eg1,const T* eb1,const T* eg2,const T* eb2,
    const T* eW1,const T* ebb1,const T* eW2,const T* ebb2, int tid, int NT){
  float* h  =P+0;     // 924
  float* qkv=P+924;   // 7*388 = 2716 -> 3640
  float* att=P+3640;  // 924 -> 4564
  float* sb =P+4564;  // 392 -> 4956
  float* ff =P+924;   // 7*516 = 3612 (aliases qkv+att, disjoint in time)
  for(int l=0;l<NLYR;l++){
    lnr(xS,SD,h,SD,eg1+l*ND,eb1+l*ND,muS,rsS,NJ,tid,NT);
    mmR<128,384,7>(h,SD,eWqkv+(size_t)l*ND*3*ND,ebqkv+l*3*ND,qkv,S384,NJ,tid,NT,0,false);
    for(int idx=tid;idx<NHD*NJ*NJ;idx+=NT){
      int hh=idx/49, r=idx%49, i=r/7, jj=r%7;
      float acc=0.f;
      const float* qr=&qkv[i*S384+hh*16];
      const float* kr=&qkv[jj*S384+128+hh*16];
      for(int d=0;d<16;d++) acc+=qr[d]*kr[d];
      sb[idx]=acc*0.25f+biasS[idx];
    }
    __syncthreads();
    if(tid<NHD*NJ){
      float* s=&sb[tid*7];
      float mx=s[0]; for(int j=1;j<7;j++) mx=fmaxf(mx,s[j]);
      float sm=0.f; for(int j=0;j<7;j++){ s[j]=expf(s[j]-mx); sm+=s[j]; }
      float inv=1.0f/sm; for(int j=0;j<7;j++) s[j]*=inv;
    }
    __syncthreads();
    for(int idx=tid;idx<NJ*ND;idx+=NT){
      int i=idx>>7, d=idx&127, hh=d>>4;
      float acc=0.f;
      for(int j=0;j<7;j++) acc+=sb[(hh*7+i)*7+j]*qkv[j*S384+256+d];
      att[i*SD+d]=acc;
    }
    __syncthreads();
    mmR<128,128,7>(att,SD,eWo+(size_t)l*ND*ND,ebo+l*ND,xS,SD,NJ,tid,NT,0,true);
    lnr(xS,SD,h,SD,eg2+l*ND,eb2+l*ND,muS,rsS,NJ,tid,NT);
    mmR<128,512,7>(h,SD,eW1+(size_t)l*ND*NFF,ebb1+l*NFF,ff,S512,NJ,tid,NT,1,false);
    mmR<512,128,7>(ff,S512,eW2+(size_t)l*NFF*ND,ebb2+l*ND,xS,SD,NJ,tid,NT,0,true);
  }
}

template<typename T>
__device__ void phase_tca(float* xS, float* P, float* muS, float* rsS, const int* trS,
    const T* tWq,const T* tbq,const T* tWk,const T* tbk,const T* tWv,const T* tbv,
    const T* tWo,const T* tbo,const T* tg1,const T* tb1,const T* tW1,const T* tbb1,
    const T* tW2,const T* tbb2,const T* tg2,const T* tb2, int tid, int NT){
  float* A   =P+0;      // 35*132 = 4620  (triplet means; dead after V)
  float* kv  =P+4620;   // 4620 -> 9240
  float* q   =P+9240;   // 924  -> 10164
  float* sb4 =P+10164;  // 980  -> 11144
  float* att2=P+0;      // 924 (A dead)
  float* tff =P+0;      // 1820 (att2 dead)
  const float sc=0.17677669529663687f;
  // triplet means
  for(int idx=tid;idx<NTR*ND;idx+=NT){
    int t=idx>>7, d=idx&127;
    A[t*SD+d]=(xS[trS[t*3]*SD+d]+xS[trS[t*3+1]*SD+d]+xS[trS[t*3+2]*SD+d])*(1.0f/3.0f);
  }
  __syncthreads();
  mmR<128,128,7>(xS,SD,tWq,tbq,q,SD,NJ,tid,NT,0,false);
  for(int rg=0;rg<5;rg++)   // K projection, 7 rows per pass
    mmR<128,128,7>(A+rg*7*SD,SD,tWk,tbk,kv+rg*7*SD,SD,7,tid,NT,0,false);
  for(int idx=tid;idx<4*NJ*NTR;idx+=NT){
    int hh=idx/245, r=idx%245, i=r/35, t=r%35;
    float acc=0.f;
    const float* qr=&q[i*SD+hh*32];
    const float* kr=&kv[t*SD+hh*32];
    for(int d=0;d<32;d++) acc+=qr[d]*kr[d];
    bool mem=(trS[t*3]==i||trS[t*3+1]==i||trS[t*3+2]==i);
    sb4[idx]=acc*sc+(mem?0.0f:-1e9f);
  }
  __syncthreads();
  if(tid<4*NJ){
    float* s=&sb4[tid*35];
    float mx=-3e38f; for(int t=0;t<35;t++) mx=fmaxf(mx,s[t]);
    float sm=0.f; for(int t=0;t<35;t++){ s[t]=expf(s[t]-mx); sm+=s[t]; }
    float inv=1.0f/sm; for(int t=0;t<35;t++) s[t]*=inv;
  }
  __syncthreads();
  for(int rg=0;rg<5;rg++)   // V projection overwrites kv (scores done)
    mmR<128,128,7>(A+rg*7*SD,SD,tWv,tbv,kv+rg*7*SD,SD,7,tid,NT,0,false);
  // A dead now; att2 aliases it
  for(int idx=tid;idx<NJ*ND;idx+=NT){
    int i=idx>>7, d=idx&127, hh=d>>5;
    float acc=0.f;
    for(int t=0;t<35;t++) acc+=sb4[(hh*7+i)*35+t]*kv[t*SD+d];
    att2[i*SD+d]=acc;
  }
  __syncthreads();
  mmR<128,128,7>(att2,SD,tWo,tbo,xS,SD,NJ,tid,NT,0,true);
  lnr(xS,SD,xS,SD,tg1,tb1,muS,rsS,NJ,tid,NT);
  mmR<128,256,7>(xS,SD,tW1,tbb1,tff,S256,NJ,tid,NT,2,false);
  mmR<256,128,7>(tff,S256,tW2,tbb2,xS,SD,NJ,tid,NT,0,true);
  lnr(xS,SD,xS,SD,tg2,tb2,muS,rsS,NJ,tid,NT);
}

// ---------------- kernels ----------------

template<typename T>
__global__ __launch_bounds__(256) void k_front(KArgs A, unsigned want, float* X2, float* EVT){
  if(((const unsigned*)A.flag)[0]!=want) return;
  int b=blockIdx.x, tid=threadIdx.x;
  __shared__ __align__(16) float xS[NJ*SD];
  __shared__ __align__(16) float biasS[NHD*NJ*NJ];
  __shared__ __align__(16) float P[11200];
  __shared__ float muS[16], rsS[16];
  __shared__ int trS[NTR*3];
  if(tid==0) build_trips(trS);
  __syncthreads();
  phase_embed((const T*)A.p[0],(const T*)A.p[1],(const T*)A.p[2],
              (const T*)A.p[3],(const T*)A.p[4],(const T*)A.p[5],xS,biasS,P,b,tid,256);
  phase_enc(xS,biasS,P,muS,rsS,
    (const T*)A.p[6],(const T*)A.p[7],(const T*)A.p[8],(const T*)A.p[9],
    (const T*)A.p[10],(const T*)A.p[11],(const T*)A.p[12],(const T*)A.p[13],
    (const T*)A.p[14],(const T*)A.p[15],(const T*)A.p[16],(const T*)A.p[17],tid,256);
  phase_tca(xS,P,muS,rsS,trS,
    (const T*)A.p[18],(const T*)A.p[19],(const T*)A.p[20],(const T*)A.p[21],
    (const T*)A.p[22],(const T*)A.p[23],(const T*)A.p[24],(const T*)A.p[25],
    (const T*)A.p[26],(const T*)A.p[27],(const T*)A.p[28],(const T*)A.p[29],
    (const T*)A.p[30],(const T*)A.p[31],(const T*)A.p[32],(const T*)A.p[33],tid,256);
  for(int idx=tid;idx<NJ*ND;idx+=256) X2[(size_t)b*NJ*ND+idx]=xS[(idx>>7)*SD+(idx&127)];
  if(tid<ND){
    float s=0.f; for(int j=0;j<NJ;j++) s+=xS[j*SD+tid];
    EVT[(size_t)b*ND+tid]=s*(1.0f/NJ);
  }
}

// group transformer: 3 triplets (9 tokens) per block, 512 threads
template<typename T>
__global__ __launch_bounds__(512,6) void k_gt(KArgs A, unsigned want, const float* X2, float* GRP){
  if(((const unsigned*)A.flag)[0]!=want) return;
  const T* gWqkv=(const T*)A.p[34]; const T* gbqkv=(const T*)A.p[35];
  const T* gWo  =(const T*)A.p[36]; const T* gbo  =(const T*)A.p[37];
  const T* gg1  =(const T*)A.p[38]; const T* gb1  =(const T*)A.p[39];
  const T* gg2  =(const T*)A.p[40]; const T* gb2  =(const T*)A.p[41];
  const T* gW1  =(const T*)A.p[42]; const T* gbb1 =(const T*)A.p[43];
  const T* gW2  =(const T*)A.p[44]; const T* gbb2 =(const T*)A.p[45];
  int b=blockIdx.x/12, ch=blockIdx.x%12, tid=threadIdx.x;
  int c0=ch*3, tc=(NTR-c0)<3?(NTR-c0):3;
  int ntok=3*tc;
  __shared__ __align__(16) float jets[NJ*SD];
  __shared__ __align__(16) float xg[9*SD];
  __shared__ __align__(16) float hg[9*SD];        // also attg
  __shared__ __align__(16) float qkvg[9*S384];    // also ffg (9*260 fits)
  __shared__ float sbg[108];
  __shared__ float muS[16], rsS[16];
  __shared__ int trS[NTR*3];
  if(tid==0) build_trips(trS);
  for(int idx=tid;idx<NJ*ND;idx+=512) jets[(idx>>7)*SD+(idx&127)]=X2[(size_t)b*NJ*ND+idx];
  __syncthreads();
  const float sc=0.17677669529663687f;
  for(int idx=tid;idx<ntok*ND;idx+=512){
    int s=idx>>7, d=idx&127; int t=c0+s/3, r=s%3;
    xg[s*SD+d]=jets[trS[t*3+r]*SD+d];
  }
  __syncthreads();
  lnr(xg,SD,hg,SD,gg1,gb1,muS,rsS,ntok,tid,512);
  mmR<128,384,9>(hg,SD,gWqkv,gbqkv,qkvg,S384,ntok,tid,512,0,false);
  for(int idx=tid;idx<tc*36;idx+=512){
    int s=idx/36, r=idx%36, hh=r/9, p=r%9, i=p/3, j=p%3;
    float acc=0.f;
    const float* qr=&qkvg[(s*3+i)*S384+hh*32];
    const float* kr=&qkvg[(s*3+j)*S384+128+hh*32];
    for(int d=0;d<32;d++) acc+=qr[d]*kr[d];
    sbg[idx]=acc*sc;
  }
  __syncthreads();
  for(int q2=tid;q2<tc*12;q2+=512){
    int s=q2/12, r2=q2%12;
    float* base=&sbg[s*36+(r2/3)*9+(r2%3)*3];
    float mx=fmaxf(base[0],fmaxf(base[1],base[2]));
    float e0=expf(base[0]-mx),e1=expf(base[1]-mx),e2=expf(base[2]-mx);
    float inv=1.0f/(e0+e1+e2);
    base[0]=e0*inv; base[1]=e1*inv; base[2]=e2*inv;
  }
  __syncthreads();
  // AV into attg (=hg; hg value no longer needed)
  for(int idx=tid;idx<ntok*ND;idx+=512){
    int sr=idx>>7, d=idx&127; int s=sr/3, i=sr%3, hh=d>>5;
    float acc=0.f;
    for(int j=0;j<3;j++) acc+=sbg[s*36+hh*9+i*3+j]*qkvg[(s*3+j)*S384+256+d];
    hg[sr*SD+d]=acc;
  }
  __syncthreads();
  mmR<128,128,9>(hg,SD,gWo,gbo,xg,SD,ntok,tid,512,0,true);
  lnr(xg,SD,hg,SD,gg2,gb2,muS,rsS,ntok,tid,512);
  mmR<128,256,9>(hg,SD,gW1,gbb1,qkvg,S256,ntok,tid,512,1,false);   // ffg aliases qkvg
  mmR<256,128,9>(qkvg,S256,gW2,gbb2,xg,SD,ntok,tid,512,0,true);
  for(int idx=tid;idx<tc*ND;idx+=512){
    int s=idx>>7, d=idx&127;
    GRP[((size_t)b*NTR+c0+s)*ND+d]=
      (xg[(s*3)*SD+d]+xg[(s*3+1)*SD+d]+xg[(s*3+2)*SD+d])*(1.0f/3.0f);
  }
}

// ---------------- LDS-staged GEMM scorer (unchanged, proven) ----------------
template<typename T>
__global__ __launch_bounds__(512) void k_score(KArgs A, unsigned want,
    const float* X2, const float* EVT, const float* GRP){
  if(((const unsigned*)A.flag)[0]!=want) return;
  const T* fm =(const T*)A.p[0];
  const T* phg=(const T*)A.p[46]; const T* phb=(const T*)A.p[47];
  const T* sW1=(const T*)A.p[48]; const T* sb1=(const T*)A.p[49];
  const T* sW2=(const T*)A.p[50]; const T* sb2=(const T*)A.p[51];
  const T* sW3=(const T*)A.p[52]; const T* sb3=(const T*)A.p[53];
  T* OUT=(T*)A.out;
  int b=blockIdx.x, tid=threadIdx.x;
  int ar=tid&7, cg=tid>>3;

  __shared__ __align__(16) float POOL[12472];
  float* grpP=POOL;
  float* Ws  =POOL+4680;
  float* h2t =POOL+4680;
  float* h1c =POOL+8776;
  float* Fc  =POOL+10096;
  float* jets=POOL+10096;
  __shared__ float physAll[72*24];
  __shared__ float isrc[7*260];
  __shared__ float evtc[256];
  __shared__ float evtS[128];
  __shared__ float fmvS[28];
  __shared__ int trS[105];
  __shared__ int isrS[72], g1tS[72], g2tS[72], g1jS[216], g2jS[216];

  if(tid==0){
    build_trips(trS); build_assign(trS,isrS,g1tS,g2tS,g1jS,g2jS);
    for(int a=70;a<72;a++){
      isrS[a]=0; g1tS[a]=0; g2tS[a]=0;
      for(int r=0;r<3;r++){ g1jS[a*3+r]=0; g2jS[a*3+r]=0; }
    }
  }
  for(int idx=tid;idx<NTR*ND;idx+=512) grpP[(idx>>7)*132+(idx&127)]=GRP[(size_t)b*NTR*ND+idx];
  for(int idx=tid;idx<NJ*ND;idx+=512) jets[idx]=X2[(size_t)b*NJ*ND+idx];
  if(tid<ND) evtS[tid]=EVT[(size_t)b*ND+tid];
  if(tid>=128&&tid<128+NJ*4){ int q=tid-128; fmvS[q]=ldv(fm,(size_t)b*NJ*4+q); }
  __syncthreads();

  {
    int i=tid&7, k4=(tid>>3)<<2;
    const float* src=(i<7)?(jets+i*ND):evtS;
    size_t rb=(i<7)?0:(size_t)4*ND;
    float acc[4];
    if(i==7) ldv4(sb1,k4,acc); else { acc[0]=0.f;acc[1]=0.f;acc[2]=0.f;acc[3]=0.f; }
    for(int d=0;d<ND;d++){
      float w[4]; ldv4(sW1,(rb+d)*2*ND+k4,w);
      float av=src[d];
      acc[0]+=av*w[0]; acc[1]+=av*w[1]; acc[2]+=av*w[2]; acc[3]+=av*w[3];
    }
    if(i<7){ int o=i*260+k4; isrc[o]=acc[0]; isrc[o+1]=acc[1]; isrc[o+2]=acc[2]; isrc[o+3]=acc[3]; }
    else   { evtc[k4]=acc[0]; evtc[k4+1]=acc[1]; evtc[k4+2]=acc[2]; evtc[k4+3]=acc[3]; }
  }
  if(tid<72*4){
    int a=tid>>2, g=tid&3;
    float* o=&physAll[a*24+g*6];
    if(a<NAS){
      float p[4];
      #pragma unroll
      for(int c=0;c<4;c++){
        float v;
        if(g==0)      v=fmvS[g1jS[a*3]*4+c]+fmvS[g1jS[a*3+1]*4+c]+fmvS[g1jS[a*3+2]*4+c];
        else if(g==1) v=fmvS[g2jS[a*3]*4+c]+fmvS[g2jS[a*3+1]*4+c]+fmvS[g2jS[a*3+2]*4+c];
        else if(g==2) v=fmvS[isrS[a]*4+c];
        else          v=fmvS[g1jS[a*3]*4+c]+fmvS[g1jS[a*3+1]*4+c]+fmvS[g1jS[a*3+2]*4+c]
                       +fmvS[g2jS[a*3]*4+c]+fmvS[g2jS[a*3+1]*4+c]+fmvS[g2jS[a*3+2]*4+c];
        p[c]=v;
      }
      float E=p[0], x_=p[1], y_=p[2], z_=p[3];
      float pt=sqrtf(x_*x_+y_*y_);
      float p3=sqrtf(pt*pt+z_*z_);
      float m =sqrtf(fmaxf(E*E-p3*p3,1e-8f));
      float eta=asinhf(z_/fmaxf(pt,1e-8f));
      float ph=atan2f(y_,x_);
      o[0]=m; o[1]=pt; o[2]=eta; o[3]=ph; o[4]=E; o[5]=p3;
    } else { o[0]=0;o[1]=0;o[2]=0;o[3]=0;o[4]=0;o[5]=0; }
  }
  __syncthreads();
  if(tid<72){
    float* o=&physAll[tid*24];
    float m=0.f; for(int c=0;c<24;c++) m+=o[c]; m*=(1.0f/24.0f);
    float v=0.f; for(int c=0;c<24;c++){ float t=o[c]-m; v+=t*t; } v*=(1.0f/24.0f);
    float r=rsqrtf(v+1e-5f);
    for(int c=0;c<24;c++) o[c]=(o[c]-m)*r*ldv(phg,c)+ldv(phb,c);
  }
  __syncthreads();

  for(int t=0;t<2;t++){
    int tbase=t*40;
    int ns=(t==0)?5:4;
    float acc[5][4];
    #pragma unroll
    for(int s=0;s<5;s++){ acc[s][0]=0.f;acc[s][1]=0.f;acc[s][2]=0.f;acc[s][3]=0.f; }

    for(int kc=0;kc<408;kc+=16){
      int csz=(408-kc)<16?(408-kc):16;
      for(int idx4=tid*4; idx4<csz*256; idx4+=2048){
        int d=idx4>>8, n=idx4&255;
        int c=kc+d;
        size_t r=(c<384)? (size_t)(ND+c) : (size_t)(5*ND+(c-384));
        float w[4]; ldv4(sW1,r*2*ND+n,w);
        Ws[d*256+n]=w[0]; Ws[d*256+n+1]=w[1]; Ws[d*256+n+2]=w[2]; Ws[d*256+n+3]=w[3];
      }
      for(int idx=tid; idx<72*16; idx+=512){
        int a=idx>>4, d=idx&15;
        if(d<csz){
          int c=kc+d;
          float f;
          if(c<384){
            int cc=c&127, kind=c>>7;
            float u=grpP[g1tS[a]*132+cc], w=grpP[g2tS[a]*132+cc];
            f=(kind==0)?(u+w):(kind==1)?(u*w):(u-w)*(u-w);
          } else f=physAll[a*24+(c-384)];
          Fc[a*17+d]=f;
        }
      }
      __syncthreads();
      for(int d=0;d<csz;d++){
        const float* wp=&Ws[d*256+(cg<<2)];
        float w0=wp[0],w1=wp[1],w2=wp[2],w3=wp[3];
        #pragma unroll
        for(int s=0;s<5;s++){
          if(s<ns){
            float f=Fc[(tbase+ar+8*s)*17+d];
            acc[s][0]+=f*w0; acc[s][1]+=f*w1; acc[s][2]+=f*w2; acc[s][3]+=f*w3;
          }
        }
      }
      __syncthreads();
    }
    float h1r[5][4];
    #pragma unroll
    for(int s=0;s<5;s++){
      if(s<ns){
        int a=tbase+ar+8*s;
        int ir=isrS[a];
        #pragma unroll
        for(int j=0;j<4;j++){
          int k=(cg<<2)+j;
          h1r[s][j]=gelu_f(acc[s][j]+evtc[k]+isrc[ir*260+k]);
        }
      } else { h1r[s][0]=0;h1r[s][1]=0;h1r[s][2]=0;h1r[s][3]=0; }
    }

    float acc2[5][4];
    {
      float b2v[4]; int k4b=(cg&31)<<2; ldv4(sb2,k4b,b2v);
      #pragma unroll
      for(int s=0;s<5;s++){ acc2[s][0]=b2v[0];acc2[s][1]=b2v[1];acc2[s][2]=b2v[2];acc2[s][3]=b2v[3]; }
    }
    for(int fc=0;fc<256;fc+=32){
      if(cg>=(fc>>2)&&cg<(fc>>2)+8){
        int dcol=(cg<<2)-fc;
        #pragma unroll
        for(int s=0;s<5;s++){
          if(s<ns){
            int al=ar+8*s;
            h1c[al*33+dcol]  =h1r[s][0];
            h1c[al*33+dcol+1]=h1r[s][1];
            h1c[al*33+dcol+2]=h1r[s][2];
            h1c[al*33+dcol+3]=h1r[s][3];
          }
        }
      }
      for(int idx4=tid*4; idx4<32*128; idx4+=2048){
        int d=idx4>>7, n=idx4&127;
        float w[4]; ldv4(sW2,(size_t)(fc+d)*128+n,w);
        Ws[d*128+n]=w[0]; Ws[d*128+n+1]=w[1]; Ws[d*128+n+2]=w[2]; Ws[d*128+n+3]=w[3];
      }
      __syncthreads();
      if(cg<32){
        for(int d=0;d<32;d++){
          const float* wp=&Ws[d*128+(cg<<2)];
          float w0=wp[0],w1=wp[1],w2=wp[2],w3=wp[3];
          #pragma unroll
          for(int s=0;s<5;s++){
            if(s<ns){
              float f=h1c[(ar+8*s)*33+d];
              acc2[s][0]+=f*w0; acc2[s][1]+=f*w1; acc2[s][2]+=f*w2; acc2[s][3]+=f*w3;
            }
          }
        }
      }
      __syncthreads();
    }
    if(cg<32){
      int k4=cg<<2;
      #pragma unroll
      for(int s=0;s<5;s++){
        if(s<ns){
          int al=ar+8*s;
          h2t[al*129+k4]  =gelu_f(acc2[s][0]);
          h2t[al*129+k4+1]=gelu_f(acc2[s][1]);
          h2t[al*129+k4+2]=gelu_f(acc2[s][2]);
          h2t[al*129+k4+3]=gelu_f(acc2[s][3]);
        }
      }
    }
    __syncthreads();
    {
      int widx=tid>>6, lane=tid&63;
      int nal=(t==0)?40:30;
      for(int s2=0;s2<5;s2++){
        int al=widx+8*s2;
        if(al<nal){
          float part=h2t[al*129+lane]*ldv(sW3,lane)+h2t[al*129+64+lane]*ldv(sW3,64+lane);
          for(int off=32;off>0;off>>=1) part+=__shfl_down(part,off,64);
          if(lane==0) stv(OUT,(size_t)b*NAS+tbase+al,part+ldv(sb3,0));
        }
      }
    }
    __syncthreads();
  }
}

extern "C" void kernel_launch(void* const* d_in, const int* in_sizes, int n_in,
                              void* d_out, int out_size, void* d_ws, size_t ws_size,
                              hipStream_t stream){
  KArgs A;
  for(int i=0;i<54;i++) A.p[i]=d_in[i];
  A.out=d_out;
  A.flag=d_ws;

  float* ws=(float*)d_ws;
  float* X2  = ws+16;
  float* EVT = X2 + (size_t)NB*NJ*ND;
  float* GRP = EVT + (size_t)NB*ND;

  k_detect<<<1,256,0,stream>>>((const unsigned short*)d_in[1],1024,(unsigned*)d_ws);

  k_front<bf16> <<<NB,256,0,stream>>>(A,0u,X2,EVT);
  k_front<float><<<NB,256,0,stream>>>(A,1u,X2,EVT);
  k_gt<bf16>    <<<NB*12,512,0,stream>>>(A,0u,X2,GRP);
  k_gt<float>   <<<NB*12,512,0,stream>>>(A,1u,X2,GRP);
  k_score<bf16> <<<NB,512,0,stream>>>(A,0u,X2,EVT,GRP);
  k_score<float><<<NB,512,0,stream>>>(A,1u,X2,EVT,GRP);
}